// Round 2
// baseline (280.101 us; speedup 1.0000x reference)
//
#include <hip/hip_runtime.h>

#define NN 8192
#define FI 256
#define FO 128
#define GAT_ALPHA 0.2f

typedef _Float16 f16x8 __attribute__((ext_vector_type(8)));
typedef float f32x4 __attribute__((ext_vector_type(4)));

// ---------------------------------------------------------------------------
// K1: Wh[j][f] = sum_k h[j][k] * W[f][k] + b[f]   (fp32, LDS-tiled)
// block: 256 thr, 32 rows of h; thread computes 4f x 4r outputs
// ---------------------------------------------------------------------------
__global__ __launch_bounds__(256) void k1_wh(const float* __restrict__ h,
                                             const float* __restrict__ W,
                                             const float* __restrict__ bias,
                                             float* __restrict__ Wh) {
  __shared__ float hs[32][FI + 1];   // +1 pad: conflict-free strided reads
  __shared__ float wt[32][FO];       // W chunk, transposed wt[k][f]
  const int t = threadIdx.x;
  const int j0 = blockIdx.x * 32;
  {
    const int row = t >> 3, c0 = (t & 7) * 32;
    const float* src = h + (size_t)(j0 + row) * FI + c0;
#pragma unroll
    for (int e = 0; e < 8; ++e) {
      float4 v = *(const float4*)(src + 4 * e);
      hs[row][c0 + 4 * e + 0] = v.x;
      hs[row][c0 + 4 * e + 1] = v.y;
      hs[row][c0 + 4 * e + 2] = v.z;
      hs[row][c0 + 4 * e + 3] = v.w;
    }
  }
  const int f4 = (t & 31) * 4;
  const int r0 = (t >> 5) * 4;
  float acc[4][4];
#pragma unroll
  for (int r = 0; r < 4; ++r)
#pragma unroll
    for (int e = 0; e < 4; ++e) acc[r][e] = 0.f;

  for (int kc = 0; kc < FI; kc += 32) {
    __syncthreads();
    {
      const int f = t >> 1, kb = (t & 1) * 16;
      const float* wsrc = W + (size_t)f * FI + kc + kb;
#pragma unroll
      for (int e = 0; e < 16; ++e) wt[kb + e][f] = wsrc[e];
    }
    __syncthreads();
#pragma unroll
    for (int k = 0; k < 32; ++k) {
      const float4 wv = *(const float4*)&wt[k][f4];
      float hv[4];
#pragma unroll
      for (int r = 0; r < 4; ++r) hv[r] = hs[r0 + r][kc + k];
#pragma unroll
      for (int r = 0; r < 4; ++r) {
        acc[r][0] += hv[r] * wv.x;
        acc[r][1] += hv[r] * wv.y;
        acc[r][2] += hv[r] * wv.z;
        acc[r][3] += hv[r] * wv.w;
      }
    }
  }
  const float4 bv = *(const float4*)&bias[f4];
#pragma unroll
  for (int r = 0; r < 4; ++r) {
    float4 o;
    o.x = acc[r][0] + bv.x;
    o.y = acc[r][1] + bv.y;
    o.z = acc[r][2] + bv.z;
    o.w = acc[r][3] + bv.w;
    *(float4*)&Wh[(size_t)(j0 + r0 + r) * FO + f4] = o;
  }
}

// ---------------------------------------------------------------------------
// K1b: s1 = Wh@a1, s2 = Wh@a2, plus exp tables:
//   r4[j] = (s1, exp(s1), exp(0.2*s1), 0)  ; c4[j] = (s2, exp(s2), exp(0.2*s2), 0)
// one wave per row
// ---------------------------------------------------------------------------
__global__ __launch_bounds__(256) void k1b_sv(const float* __restrict__ Wh,
                                              const float* __restrict__ a,
                                              float4* __restrict__ r4,
                                              float4* __restrict__ c4) {
  const int lane = threadIdx.x & 63;
  const int j = blockIdx.x * 4 + (threadIdx.x >> 6);
  const float* row = Wh + (size_t)j * FO;
  const float w0 = row[lane], w1 = row[lane + 64];
  float s1 = w0 * a[lane] + w1 * a[lane + 64];
  float s2 = w0 * a[FO + lane] + w1 * a[FO + lane + 64];
#pragma unroll
  for (int o = 32; o >= 1; o >>= 1) {
    s1 += __shfl_xor(s1, o);
    s2 += __shfl_xor(s2, o);
  }
  if (lane == 0) {
    float4 rv;
    rv.x = s1; rv.y = expf(s1); rv.z = expf(GAT_ALPHA * s1); rv.w = 0.f;
    float4 cv;
    cv.x = s2; cv.y = expf(s2); cv.z = expf(GAT_ALPHA * s2); cv.w = 0.f;
    r4[j] = rv;
    c4[j] = cv;
  }
}

// ---------------------------------------------------------------------------
// K2: single pass over adj (268 MB, the HBM floor):
//   - pack row-major bitmask via __ballot (8 MB)
//   - per-column partial sums: accP = sum_{act, x>=0} exp(s1_i),
//                              accN = sum_{act, x<0 } exp(0.2*s1_i)
// grid: 32 j-chunks(256 wide) x 16 i-chunks(512 tall) = 512 blocks
// ---------------------------------------------------------------------------
__global__ __launch_bounds__(256) void k2_stats(const int* __restrict__ adj,
                                                const float4* __restrict__ r4,
                                                const float4* __restrict__ c4,
                                                unsigned long long* __restrict__ bits,
                                                float2* __restrict__ zpart) {
  __shared__ float4 rs[512];
  const int t = threadIdx.x;
  const int jc = blockIdx.x & 31;
  const int ic = blockIdx.x >> 5;
  const int j0 = jc * 256;
  const int i0 = ic * 512;
  for (int e = t; e < 512; e += 256) rs[e] = r4[i0 + e];
  __syncthreads();
  const int j = j0 + t;
  const float4 cj = c4[j];
  float accP = 0.f, accN = 0.f;
  const int wv = t >> 6;
  const int* ap = adj + (size_t)i0 * NN + j;
  unsigned long long* bp = bits + (size_t)i0 * (NN / 64) + (j0 >> 6) + wv;
  for (int ir = 0; ir < 512; ir += 16) {
    int av[16];
#pragma unroll
    for (int u = 0; u < 16; ++u) av[u] = ap[(ir + u) * NN];
#pragma unroll
    for (int u = 0; u < 16; ++u) {
      const float4 ri = rs[ir + u];
      const bool act = av[u] > 0;
      const unsigned long long m = __ballot(act);
      if ((t & 63) == 0) bp[(size_t)(ir + u) * (NN / 64)] = m;
      const float x = ri.x + cj.x;
      const bool pos = x >= 0.f;
      accP += (act && pos) ? ri.y : 0.f;
      accN += (act && !pos) ? ri.z : 0.f;
    }
  }
  float2 z;
  z.x = accP;
  z.y = accN;
  zpart[(size_t)ic * NN + j] = z;
}

// ---------------------------------------------------------------------------
// K3: Z_j = E2p*sum(accP) + E2n*sum(accN); WhT[f][j] = fp16(Wh[j][f]/Z_j)
// empty columns (Z==0): WhT row = 0, corr[f] += Wh[j][f]/N  (exact uniform-softmax fix)
// block: 64 j's, transpose through LDS
// ---------------------------------------------------------------------------
__global__ __launch_bounds__(256) void k3_scale(const float* __restrict__ Wh,
                                                const float4* __restrict__ c4,
                                                const float2* __restrict__ zpart,
                                                _Float16* __restrict__ WhT,
                                                float* __restrict__ corr) {
  __shared__ float rz[64];
  __shared__ int emp[64];
  __shared__ _Float16 tile[FO][72];
  const int t = threadIdx.x;
  const int j0 = blockIdx.x * 64;
  if (t < 64) {
    const int j = j0 + t;
    float p = 0.f, n = 0.f;
#pragma unroll
    for (int ic = 0; ic < 16; ++ic) {
      const float2 z = zpart[(size_t)ic * NN + j];
      p += z.x;
      n += z.y;
    }
    const float4 cj = c4[j];
    const float Z = cj.y * p + cj.z * n;
    rz[t] = (Z > 0.f) ? 1.f / Z : 0.f;
    emp[t] = (Z > 0.f) ? 0 : 1;
  }
  __syncthreads();
  const int f = t & 127, half = t >> 7;
  for (int r = half; r < 64; r += 2) {
    const float v = Wh[(size_t)(j0 + r) * FO + f];
    tile[f][r] = (_Float16)(v * rz[r]);
    if (emp[r]) atomicAdd(&corr[f], v * (1.f / 8192.f));
  }
  __syncthreads();
  const int fo = t >> 1, p2 = (t & 1) * 32;
  const float4* srcv = (const float4*)&tile[fo][p2];
  float4* dstv = (float4*)(WhT + (size_t)fo * NN + j0 + p2);
#pragma unroll
  for (int e = 0; e < 4; ++e) dstv[e] = srcv[e];
}

// ---------------------------------------------------------------------------
// K4: out[i][f] = elu( sum_j P~[i][j] * WhT[f][j] + corr[f] )
//   P~[i][j] = bit(i,j) * (x>=0 ? e^{s1} e^{s2} : e^{0.2 s1} e^{0.2 s2})  (fp16)
// block: 512 thr (8 waves 2x4), 32 output rows, K-steps of 128 columns,
// double-buffered LDS P tile with XOR-16B swizzle; mfma_f32_16x16x32_f16
// ---------------------------------------------------------------------------
__global__ __launch_bounds__(512) void k4_main(const unsigned char* __restrict__ bitsB,
                                               const float4* __restrict__ r4,
                                               const float4* __restrict__ c4,
                                               const _Float16* __restrict__ WhT,
                                               const float* __restrict__ corr,
                                               float* __restrict__ out) {
  __shared__ __align__(16) char Plc[2][32 * 256];  // 32 rows x 128 f16 per buf
  __shared__ float4 cjs[2][128];
  __shared__ float4 ris[32];
  const int t = threadIdx.x;
  const int i0 = blockIdx.x * 32;
  if (t < 32) ris[t] = r4[i0 + t];
  if (t < 128) cjs[0][t] = c4[t];
  else if (t < 256) cjs[1][t - 128] = c4[t];  // c4[128 + (t-128)]

  const int pr = t >> 4, jg = t & 15;  // P-gen: row, j-group (strided j = jg+16e)
  const unsigned char* brow = bitsB + (size_t)(i0 + pr) * (NN / 8);
  uint4 bb = *(const uint4*)(brow);  // bits for step 0

  const int lane = t & 63;
  const int wave = t >> 6;
  const int wr = wave >> 2, wc = wave & 3;
  const int arow = wr * 16 + (lane & 15);
  const int kgrp = lane >> 4;
  const int fb0 = wc * 32 + (lane & 15);
  f32x4 acc0 = {0.f, 0.f, 0.f, 0.f};
  f32x4 acc1 = {0.f, 0.f, 0.f, 0.f};
  __syncthreads();
  const float4 ri = ris[pr];
  const unsigned sw = (unsigned)((pr & 7) << 4);

  // P-gen step 0
  {
    const float4* cj = cjs[0];
    char* pb = &Plc[0][0];
    const unsigned bw0 = bb.x, bw1 = bb.y, bw2 = bb.z, bw3 = bb.w;
#pragma unroll
    for (int e = 0; e < 8; ++e) {
      const int jl = jg + 16 * e;
      const float4 c = cj[jl];
      const float x = ri.x + c.x;
      const bool pos = x >= 0.f;
      float w = (pos ? ri.y : ri.z) * (pos ? c.y : c.z);
      const unsigned wsel = (e < 2) ? bw0 : (e < 4) ? bw1 : (e < 6) ? bw2 : bw3;
      const unsigned bit = (wsel >> (jg + 16 * (e & 1))) & 1u;
      w = bit ? w : 0.f;
      *(_Float16*)(pb + pr * 256 + ((2u * (unsigned)jl) ^ sw)) = (_Float16)w;
    }
  }
  __syncthreads();
  const unsigned asw = (unsigned)((arow & 7) << 4);

  for (int s = 0; s < 64; ++s) {
    uint4 bbn;
    const bool havegen = (s + 1 < 64);
    if (havegen) bbn = *(const uint4*)(brow + (s + 1) * 16);
    if (t < 128 && s + 2 < 64) cjs[s & 1][t] = c4[(s + 2) * 128 + t];

    // MFMA phase on Plc[s&1]
    {
      const char* pb = &Plc[s & 1][0];
      const _Float16* wbase = WhT + (size_t)fb0 * NN + s * 128 + kgrp * 8;
#pragma unroll
      for (int ks = 0; ks < 4; ++ks) {
        const f16x8 af =
            *(const f16x8*)(pb + arow * 256 + (((unsigned)(ks * 64 + kgrp * 16)) ^ asw));
        const f16x8 b0 = *(const f16x8*)(wbase + ks * 32);
        const f16x8 b1 = *(const f16x8*)(wbase + ks * 32 + 16 * NN);
        acc0 = __builtin_amdgcn_mfma_f32_16x16x32_f16(af, b0, acc0, 0, 0, 0);
        acc1 = __builtin_amdgcn_mfma_f32_16x16x32_f16(af, b1, acc1, 0, 0, 0);
      }
    }

    // P-gen step s+1 into other buffer
    if (havegen) {
      const float4* cj = cjs[(s + 1) & 1];
      char* pb = &Plc[(s + 1) & 1][0];
      const unsigned bw0 = bbn.x, bw1 = bbn.y, bw2 = bbn.z, bw3 = bbn.w;
#pragma unroll
      for (int e = 0; e < 8; ++e) {
        const int jl = jg + 16 * e;
        const float4 c = cj[jl];
        const float x = ri.x + c.x;
        const bool pos = x >= 0.f;
        float w = (pos ? ri.y : ri.z) * (pos ? c.y : c.z);
        const unsigned wsel = (e < 2) ? bw0 : (e < 4) ? bw1 : (e < 6) ? bw2 : bw3;
        const unsigned bit = (wsel >> (jg + 16 * (e & 1))) & 1u;
        w = bit ? w : 0.f;
        *(_Float16*)(pb + pr * 256 + ((2u * (unsigned)jl) ^ sw)) = (_Float16)w;
      }
    }
    __syncthreads();
  }

  // epilogue: + corr, ELU, store
  const float c0 = corr[fb0];
  const float c1 = corr[fb0 + 16];
  const int ib = i0 + wr * 16 + kgrp * 4;
#pragma unroll
  for (int r2 = 0; r2 < 4; ++r2) {
    float v0 = acc0[r2] + c0;
    float v1 = acc1[r2] + c1;
    v0 = (v0 > 0.f) ? v0 : (expf(v0) - 1.f);
    v1 = (v1 > 0.f) ? v1 : (expf(v1) - 1.f);
    out[(size_t)(ib + r2) * FO + fb0] = v0;
    out[(size_t)(ib + r2) * FO + fb0 + 16] = v1;
  }
}

// ---------------------------------------------------------------------------
extern "C" void kernel_launch(void* const* d_in, const int* in_sizes, int n_in,
                              void* d_out, int out_size, void* d_ws, size_t ws_size,
                              hipStream_t stream) {
  const float* h = (const float*)d_in[0];
  const int* adj = (const int*)d_in[1];
  const float* W = (const float*)d_in[2];
  const float* b = (const float*)d_in[3];
  const float* a = (const float*)d_in[4];
  float* out = (float*)d_out;
  char* ws = (char*)d_ws;

  // workspace carve (~15.3 MB total)
  float* Wh = (float*)(ws + 0);                                  // 4 MB
  _Float16* WhT = (_Float16*)(ws + 4194304);                     // 2 MB
  float4* r4 = (float4*)(ws + 6291456);                          // 128 KB
  float4* c4 = (float4*)(ws + 6422528);                          // 128 KB
  unsigned long long* bits = (unsigned long long*)(ws + 6553600);// 8 MB
  float2* zpart = (float2*)(ws + 14942208);                      // 1 MB
  float* corr = (float*)(ws + 15990784);                         // 512 B

  hipMemsetAsync(corr, 0, FO * sizeof(float), stream);
  k1_wh<<<NN / 32, 256, 0, stream>>>(h, W, b, Wh);
  k1b_sv<<<NN / 4, 256, 0, stream>>>(Wh, a, r4, c4);
  k2_stats<<<512, 256, 0, stream>>>(adj, r4, c4, bits, zpart);
  k3_scale<<<NN / 64, 256, 0, stream>>>(Wh, c4, zpart, WhT, corr);
  k4_main<<<NN / 32, 512, 0, stream>>>((const unsigned char*)bits, r4, c4, WhT, corr, out);
}

// Round 4
// 163.479 us; speedup vs baseline: 1.7134x; 1.7134x over previous
//
#include <hip/hip_runtime.h>

#define NN 8192
#define FI 256
#define FO 128
#define GAT_ALPHA 0.2f

typedef _Float16 f16x8 __attribute__((ext_vector_type(8)));
typedef _Float16 f16x2 __attribute__((ext_vector_type(2)));
typedef float f32x4 __attribute__((ext_vector_type(4)));
typedef unsigned char uchar;
typedef unsigned int uint32;

// ---------------------------------------------------------------------------
// K1: Wh[j][f] = sum_k h[j][k] * W[f][k] + b[f]   (fp32, LDS-tiled)
// ---------------------------------------------------------------------------
__global__ __launch_bounds__(256) void k1_wh(const float* __restrict__ h,
                                             const float* __restrict__ W,
                                             const float* __restrict__ bias,
                                             float* __restrict__ Wh) {
  __shared__ float hs[32][FI + 1];
  __shared__ float wt[32][FO];
  const int t = threadIdx.x;
  const int j0 = blockIdx.x * 32;
  {
    const int row = t >> 3, c0 = (t & 7) * 32;
    const float* src = h + (size_t)(j0 + row) * FI + c0;
#pragma unroll
    for (int e = 0; e < 8; ++e) {
      float4 v = *(const float4*)(src + 4 * e);
      hs[row][c0 + 4 * e + 0] = v.x;
      hs[row][c0 + 4 * e + 1] = v.y;
      hs[row][c0 + 4 * e + 2] = v.z;
      hs[row][c0 + 4 * e + 3] = v.w;
    }
  }
  const int f4 = (t & 31) * 4;
  const int r0 = (t >> 5) * 4;
  float acc[4][4];
#pragma unroll
  for (int r = 0; r < 4; ++r)
#pragma unroll
    for (int e = 0; e < 4; ++e) acc[r][e] = 0.f;

  for (int kc = 0; kc < FI; kc += 32) {
    __syncthreads();
    {
      const int f = t >> 1, kb = (t & 1) * 16;
      const float* wsrc = W + (size_t)f * FI + kc + kb;
#pragma unroll
      for (int e = 0; e < 16; ++e) wt[kb + e][f] = wsrc[e];
    }
    __syncthreads();
#pragma unroll
    for (int k = 0; k < 32; ++k) {
      const float4 wv = *(const float4*)&wt[k][f4];
      float hv[4];
#pragma unroll
      for (int r = 0; r < 4; ++r) hv[r] = hs[r0 + r][kc + k];
#pragma unroll
      for (int r = 0; r < 4; ++r) {
        acc[r][0] += hv[r] * wv.x;
        acc[r][1] += hv[r] * wv.y;
        acc[r][2] += hv[r] * wv.z;
        acc[r][3] += hv[r] * wv.w;
      }
    }
  }
  const float4 bv = *(const float4*)&bias[f4];
#pragma unroll
  for (int r = 0; r < 4; ++r) {
    float4 o;
    o.x = acc[r][0] + bv.x;
    o.y = acc[r][1] + bv.y;
    o.z = acc[r][2] + bv.z;
    o.w = acc[r][3] + bv.w;
    *(float4*)&Wh[(size_t)(j0 + r0 + r) * FO + f4] = o;
  }
}

// ---------------------------------------------------------------------------
// K1b: s1/s2 scores + exp tables.
//  r4[j]=(s1, e^s1, e^.2s1, 0)  c4[j]=(s2, e^s2, e^.2s2, 0)
//  r2[j]=(e^s1, e^.2s1) f32     c2h[j]=packed f16 (e^s2, e^.2s2)
// ---------------------------------------------------------------------------
__global__ __launch_bounds__(256) void k1b_sv(const float* __restrict__ Wh,
                                              const float* __restrict__ a,
                                              float4* __restrict__ r4,
                                              float4* __restrict__ c4,
                                              float2* __restrict__ r2,
                                              uint32* __restrict__ c2h) {
  const int lane = threadIdx.x & 63;
  const int j = blockIdx.x * 4 + (threadIdx.x >> 6);
  const float* row = Wh + (size_t)j * FO;
  const float w0 = row[lane], w1 = row[lane + 64];
  float s1 = w0 * a[lane] + w1 * a[lane + 64];
  float s2 = w0 * a[FO + lane] + w1 * a[FO + lane + 64];
#pragma unroll
  for (int o = 32; o >= 1; o >>= 1) {
    s1 += __shfl_xor(s1, o);
    s2 += __shfl_xor(s2, o);
  }
  if (lane == 0) {
    const float e1 = expf(s1), e1a = expf(GAT_ALPHA * s1);
    const float e2 = expf(s2), e2a = expf(GAT_ALPHA * s2);
    float4 rv; rv.x = s1; rv.y = e1; rv.z = e1a; rv.w = 0.f;
    float4 cv; cv.x = s2; cv.y = e2; cv.z = e2a; cv.w = 0.f;
    r4[j] = rv;
    c4[j] = cv;
    r2[j] = make_float2(e1, e1a);
    f16x2 cp; cp.x = (_Float16)e2; cp.y = (_Float16)e2a;
    c2h[j] = __builtin_bit_cast(uint32, cp);
  }
}

// ---------------------------------------------------------------------------
// K2: single pass over adj (268 MB HBM floor): pack row-major bitmask via
// __ballot; per-column partial Z sums (sign-split so c-factor hoists).
// ---------------------------------------------------------------------------
__global__ __launch_bounds__(256) void k2_stats(const int* __restrict__ adj,
                                                const float4* __restrict__ r4,
                                                const float4* __restrict__ c4,
                                                unsigned long long* __restrict__ bits,
                                                float2* __restrict__ zpart) {
  __shared__ float4 rs[512];
  const int t = threadIdx.x;
  const int jc = blockIdx.x & 31;
  const int ic = blockIdx.x >> 5;
  const int j0 = jc * 256;
  const int i0 = ic * 512;
  for (int e = t; e < 512; e += 256) rs[e] = r4[i0 + e];
  __syncthreads();
  const int j = j0 + t;
  const float4 cj = c4[j];
  float accP = 0.f, accN = 0.f;
  const int wv = t >> 6;
  const int* ap = adj + (size_t)i0 * NN + j;
  unsigned long long* bp = bits + (size_t)i0 * (NN / 64) + (j0 >> 6) + wv;
  for (int ir = 0; ir < 512; ir += 16) {
    int av[16];
#pragma unroll
    for (int u = 0; u < 16; ++u) av[u] = ap[(ir + u) * NN];
#pragma unroll
    for (int u = 0; u < 16; ++u) {
      const float4 ri = rs[ir + u];
      const bool act = av[u] > 0;
      const unsigned long long m = __ballot(act);
      if ((t & 63) == 0) bp[(size_t)(ir + u) * (NN / 64)] = m;
      const float x = ri.x + cj.x;
      const bool pos = x >= 0.f;
      accP += (act && pos) ? ri.y : 0.f;
      accN += (act && !pos) ? ri.z : 0.f;
    }
  }
  float2 z;
  z.x = accP;
  z.y = accN;
  zpart[(size_t)ic * NN + j] = z;
}

// ---------------------------------------------------------------------------
// K3: Z_j from partials; emit Wfrag = (Wh[j][f]/Z_j) in MFMA-B-fragment-major
// layout: granule g=(kchunk*8+fb)*64+lane holds 8 f16: f=fb*16+(lane&15),
// j=kchunk*32+(lane>>4)*8+e.  Empty cols -> corr[f] (uniform softmax fix).
// ---------------------------------------------------------------------------
__global__ __launch_bounds__(256) void k3_scale(const float* __restrict__ Wh,
                                                const float4* __restrict__ c4,
                                                const float2* __restrict__ zpart,
                                                _Float16* __restrict__ Wfrag,
                                                float* __restrict__ corr) {
  __shared__ float rz[64];
  __shared__ int emp[64];
  __shared__ __align__(16) _Float16 tile[FO * 64];  // [f][64 j], 128B rows, XOR-swz
  const int t = threadIdx.x;
  const int j0 = blockIdx.x * 64;
  if (t < 64) {
    const int j = j0 + t;
    float p = 0.f, n = 0.f;
#pragma unroll
    for (int ic = 0; ic < 16; ++ic) {
      const float2 z = zpart[(size_t)ic * NN + j];
      p += z.x;
      n += z.y;
    }
    const float4 cj = c4[j];
    const float Z = cj.y * p + cj.z * n;
    rz[t] = (Z > 0.f) ? 1.f / Z : 0.f;
    emp[t] = (Z > 0.f) ? 0 : 1;
  }
  __syncthreads();
  const int f = t & 127, half = t >> 7;
  const unsigned swf = (unsigned)((f & 7) << 4);
  for (int r = half; r < 64; r += 2) {
    const float v = Wh[(size_t)(j0 + r) * FO + f];
    *(_Float16*)((char*)tile + f * 128 + (((unsigned)(r * 2)) ^ swf)) =
        (_Float16)(v * rz[r]);
    if (emp[r]) atomicAdd(&corr[f], v * (1.f / 8192.f));
  }
  __syncthreads();
#pragma unroll
  for (int q = 0; q < 4; ++q) {
    const int G = t + 256 * q;
    const int kcfb = G >> 6, gl = G & 63;
    const int kc = kcfb >> 3, fb = kcfb & 7;
    const int gf = fb * 16 + (gl & 15);
    const int jloc = kc * 32 + (gl >> 4) * 8;
    const f16x8 v = *(const f16x8*)((const char*)tile + gf * 128 +
                                    (((unsigned)(jloc * 2)) ^ ((unsigned)((gf & 7) << 4))));
    ((f16x8*)Wfrag)[(size_t)(((j0 >> 5) + kc) * 8 + fb) * 64 + gl] = v;
  }
}

// ---------------------------------------------------------------------------
// K4: partial h' = P~ @ (Wh/Z) over this block's K-range, atomic f32 accum.
//   P~[i][j] = bit(i,j) * max(e^{s1}e^{s2}, e^{.2s1}e^{.2s2})   (== exp LReLU)
// BM=64 rows, ksplit=4 (2048 cols each, 32 steps of 64). 512 thr = 8 waves
// (2 wr x 4 wc, wave tile 32r x 32f). P via swizzled LDS (conflict-free b128),
// B-frags direct global (fragment-major, coalesced), all inputs reg-prefetched.
// ---------------------------------------------------------------------------
__global__ __launch_bounds__(512, 4) void k4_main(const uchar* __restrict__ bitsB,
                                                  const float2* __restrict__ r2,
                                                  const uint32* __restrict__ c2h,
                                                  const _Float16* __restrict__ Wfrag,
                                                  float* __restrict__ accum) {
  __shared__ __align__(16) _Float16 P[2][64 * 64];  // [row][64 k], 128B rows, XOR-swz
  const int t = threadIdx.x;
  const int rowtile = blockIdx.x >> 2;
  const int kq = blockIdx.x & 3;
  const int rowbase = rowtile * 64;
  const int koff = kq * 2048;

  // ---- P-gen thread ids: row pr, 8 consecutive j at jq*8
  const int pr = t >> 3, jq = t & 7;
  const float2 rr = r2[rowbase + pr];
  const uchar* bp = bitsB + (size_t)(rowbase + pr) * (NN / 8) + (koff >> 3) + jq;
  const uint32* cp = c2h + koff + jq * 8;
  char* const pdst0 = (char*)&P[0][0] + pr * 128 + (((unsigned)(jq * 16)) ^ ((unsigned)((pr & 7) << 4)));
  char* const pdst1 = (char*)&P[1][0] + pr * 128 + (((unsigned)(jq * 16)) ^ ((unsigned)((pr & 7) << 4)));

  // ---- MFMA ids
  const int lane = t & 63, wave = t >> 6;
  const int wr = wave >> 2, wc = wave & 3;
  const int kgrp = lane >> 4, l15 = lane & 15;
  const unsigned asw = (unsigned)((l15 & 7) << 4);
  const int ar0 = (wr * 32 + l15) * 128;
  const int ar1 = ar0 + 16 * 128;

  f32x4 acc00 = {0.f, 0.f, 0.f, 0.f}, acc01 = {0.f, 0.f, 0.f, 0.f};
  f32x4 acc10 = {0.f, 0.f, 0.f, 0.f}, acc11 = {0.f, 0.f, 0.f, 0.f};

  uchar mb0, mb1;
  uint32 c0a[4], c0b[4], c1a[4], c1b[4];
  f16x8 B000, B001, B010, B011, B100, B101, B110, B111;

#define LOADALL(S, MB, CA, CB, Bq00, Bq01, Bq10, Bq11)                              \
  do {                                                                              \
    MB = bp[(S) * 8];                                                               \
    const uint4 _ca = *(const uint4*)(cp + (S) * 64);                               \
    const uint4 _cb = *(const uint4*)(cp + (S) * 64 + 4);                           \
    CA[0] = _ca.x; CA[1] = _ca.y; CA[2] = _ca.z; CA[3] = _ca.w;                     \
    CB[0] = _cb.x; CB[1] = _cb.y; CB[2] = _cb.z; CB[3] = _cb.w;                     \
    const _Float16* _b = Wfrag + ((size_t)((kq * 64 + (S) * 2) * 8 + wc * 2) * 64 + lane) * 8; \
    Bq00 = *(const f16x8*)(_b);                                                     \
    Bq01 = *(const f16x8*)(_b + 512);                                               \
    Bq10 = *(const f16x8*)(_b + 4096);                                              \
    Bq11 = *(const f16x8*)(_b + 4096 + 512);                                        \
  } while (0)

#define PGEN(DST, MB, CA, CB)                                                       \
  do {                                                                              \
    union { f16x2 h[4]; f16x8 v; } U;                                               \
    _Pragma("unroll") for (int _p = 0; _p < 4; ++_p) {                              \
      const uint32 cv0 = (_p < 2) ? CA[2 * _p] : CB[2 * (_p - 2)];                  \
      const uint32 cv1 = (_p < 2) ? CA[2 * _p + 1] : CB[2 * (_p - 2) + 1];          \
      const f16x2 ch0 = __builtin_bit_cast(f16x2, cv0);                             \
      const f16x2 ch1 = __builtin_bit_cast(f16x2, cv1);                             \
      const float m0 = fmaxf(rr.x * (float)ch0.x, rr.y * (float)ch0.y);             \
      const float m1 = fmaxf(rr.x * (float)ch1.x, rr.y * (float)ch1.y);             \
      const float w0 = ((MB >> (2 * _p)) & 1) ? m0 : 0.f;                           \
      const float w1 = ((MB >> (2 * _p + 1)) & 1) ? m1 : 0.f;                       \
      U.h[_p] = __builtin_bit_cast(f16x2, __builtin_amdgcn_cvt_pkrtz(w0, w1));      \
    }                                                                               \
    *(f16x8*)(DST) = U.v;                                                           \
  } while (0)

#define DO_MFMA(BUF, Bq00, Bq01, Bq10, Bq11)                                        \
  do {                                                                              \
    const char* _Pb = (const char*)&P[BUF][0];                                      \
    const f16x8 a00 = *(const f16x8*)(_Pb + ar0 + ((((unsigned)(kgrp * 16))) ^ asw));        \
    const f16x8 a01 = *(const f16x8*)(_Pb + ar0 + (((unsigned)(64 + kgrp * 16)) ^ asw));     \
    const f16x8 a10 = *(const f16x8*)(_Pb + ar1 + ((((unsigned)(kgrp * 16))) ^ asw));        \
    const f16x8 a11 = *(const f16x8*)(_Pb + ar1 + (((unsigned)(64 + kgrp * 16)) ^ asw));     \
    acc00 = __builtin_amdgcn_mfma_f32_16x16x32_f16(a00, Bq00, acc00, 0, 0, 0);      \
    acc01 = __builtin_amdgcn_mfma_f32_16x16x32_f16(a00, Bq01, acc01, 0, 0, 0);      \
    acc10 = __builtin_amdgcn_mfma_f32_16x16x32_f16(a10, Bq00, acc10, 0, 0, 0);      \
    acc11 = __builtin_amdgcn_mfma_f32_16x16x32_f16(a10, Bq01, acc11, 0, 0, 0);      \
    acc00 = __builtin_amdgcn_mfma_f32_16x16x32_f16(a01, Bq10, acc00, 0, 0, 0);      \
    acc01 = __builtin_amdgcn_mfma_f32_16x16x32_f16(a01, Bq11, acc01, 0, 0, 0);      \
    acc10 = __builtin_amdgcn_mfma_f32_16x16x32_f16(a11, Bq10, acc10, 0, 0, 0);      \
    acc11 = __builtin_amdgcn_mfma_f32_16x16x32_f16(a11, Bq11, acc11, 0, 0, 0);      \
  } while (0)

  // ---- prologue
  LOADALL(0, mb0, c0a, c0b, B000, B001, B010, B011);
  LOADALL(1, mb1, c1a, c1b, B100, B101, B110, B111);
  PGEN(pdst0, mb0, c0a, c0b);
  __syncthreads();

  for (int s = 0; s < 32; s += 2) {
    // ---- even body: step s
    PGEN(pdst1, mb1, c1a, c1b);                       // step s+1
    DO_MFMA(0, B000, B001, B010, B011);               // step s
    if (s + 2 < 32) LOADALL(s + 2, mb0, c0a, c0b, B000, B001, B010, B011);
    __syncthreads();
    // ---- odd body: step s+1
    DO_MFMA(1, B100, B101, B110, B111);               // step s+1
    if (s + 2 < 32) PGEN(pdst0, mb0, c0a, c0b);       // step s+2
    if (s + 3 < 32) LOADALL(s + 3, mb1, c1a, c1b, B100, B101, B110, B111);
    __syncthreads();
  }

#undef LOADALL
#undef PGEN
#undef DO_MFMA

  // ---- epilogue: atomic accumulate partial C
  const int orow = rowbase + wr * 32 + kgrp * 4;
  const int ocol = wc * 32 + l15;
  float* aP = accum + (size_t)orow * FO + ocol;
#pragma unroll
  for (int r = 0; r < 4; ++r) {
    atomicAdd(aP + (size_t)r * FO, acc00[r]);
    atomicAdd(aP + (size_t)r * FO + 16, acc01[r]);
    atomicAdd(aP + (size_t)(16 + r) * FO, acc10[r]);
    atomicAdd(aP + (size_t)(16 + r) * FO + 16, acc11[r]);
  }
}

// ---------------------------------------------------------------------------
// K5: out = elu(accum + corr)
// ---------------------------------------------------------------------------
__global__ __launch_bounds__(256) void k5_fin(const float* __restrict__ accum,
                                              const float* __restrict__ corr,
                                              float* __restrict__ out) {
  const int idx = blockIdx.x * 256 + threadIdx.x;  // float4 index, 262144 total
  float4 v = ((const float4*)accum)[idx];
  const float4 c = ((const float4*)corr)[idx & 31];
  v.x += c.x; v.y += c.y; v.z += c.z; v.w += c.w;
  v.x = (v.x > 0.f) ? v.x : (expf(v.x) - 1.f);
  v.y = (v.y > 0.f) ? v.y : (expf(v.y) - 1.f);
  v.z = (v.z > 0.f) ? v.z : (expf(v.z) - 1.f);
  v.w = (v.w > 0.f) ? v.w : (expf(v.w) - 1.f);
  ((float4*)out)[idx] = v;
}

// ---------------------------------------------------------------------------
extern "C" void kernel_launch(void* const* d_in, const int* in_sizes, int n_in,
                              void* d_out, int out_size, void* d_ws, size_t ws_size,
                              hipStream_t stream) {
  const float* h = (const float*)d_in[0];
  const int* adj = (const int*)d_in[1];
  const float* W = (const float*)d_in[2];
  const float* b = (const float*)d_in[3];
  const float* a = (const float*)d_in[4];
  float* out = (float*)d_out;
  char* ws = (char*)d_ws;

  // workspace carve (~15.4 MB total); accum reuses the Wh region after K3.
  float* Wh = (float*)(ws + 0);                                   // 4 MB
  float* accum = (float*)(ws + 0);                                // 4 MB (after K3)
  _Float16* Wfrag = (_Float16*)(ws + 4194304);                    // 2 MB
  unsigned long long* bits = (unsigned long long*)(ws + 6291456); // 8 MB
  float2* zpart = (float2*)(ws + 14680064);                       // 1 MB
  float4* r4 = (float4*)(ws + 15728640);                          // 128 KB
  float4* c4 = (float4*)(ws + 15859712);                          // 128 KB
  float2* r2 = (float2*)(ws + 15990784);                          // 64 KB
  uint32* c2h = (uint32*)(ws + 16056320);                         // 32 KB
  float* corr = (float*)(ws + 16089088);                          // 512 B

  hipMemsetAsync(corr, 0, FO * sizeof(float), stream);
  k1_wh<<<NN / 32, 256, 0, stream>>>(h, W, b, Wh);
  k1b_sv<<<NN / 4, 256, 0, stream>>>(Wh, a, r4, c4, r2, c2h);
  k2_stats<<<512, 256, 0, stream>>>(adj, r4, c4, bits, zpart);
  k3_scale<<<NN / 64, 256, 0, stream>>>(Wh, c4, zpart, Wfrag, corr);
  hipMemsetAsync(accum, 0, (size_t)NN * FO * sizeof(float), stream);
  k4_main<<<512, 512, 0, stream>>>((const uchar*)bits, r2, c2h, Wfrag, accum);
  k5_fin<<<(NN * FO / 4) / 256, 256, 0, stream>>>(accum, corr, out);
}

// Round 5
// 150.472 us; speedup vs baseline: 1.8615x; 1.0864x over previous
//
#include <hip/hip_runtime.h>

#define NN 8192
#define FI 256
#define FO 128
#define GAT_ALPHA 0.2f

typedef _Float16 f16x8 __attribute__((ext_vector_type(8)));
typedef _Float16 f16x2 __attribute__((ext_vector_type(2)));
typedef float f32x4 __attribute__((ext_vector_type(4)));
typedef unsigned char uchar;
typedef unsigned int uint32;

// ---------------------------------------------------------------------------
// K1: Wh[j][f] = sum_k h[j][k] * W[f][k] + b[f]   (fp32, LDS-tiled)
// ---------------------------------------------------------------------------
__global__ __launch_bounds__(256) void k1_wh(const float* __restrict__ h,
                                             const float* __restrict__ W,
                                             const float* __restrict__ bias,
                                             float* __restrict__ Wh) {
  __shared__ float hs[32][FI + 1];
  __shared__ float wt[32][FO];
  const int t = threadIdx.x;
  const int j0 = blockIdx.x * 32;
  {
    const int row = t >> 3, c0 = (t & 7) * 32;
    const float* src = h + (size_t)(j0 + row) * FI + c0;
#pragma unroll
    for (int e = 0; e < 8; ++e) {
      float4 v = *(const float4*)(src + 4 * e);
      hs[row][c0 + 4 * e + 0] = v.x;
      hs[row][c0 + 4 * e + 1] = v.y;
      hs[row][c0 + 4 * e + 2] = v.z;
      hs[row][c0 + 4 * e + 3] = v.w;
    }
  }
  const int f4 = (t & 31) * 4;
  const int r0 = (t >> 5) * 4;
  float acc[4][4];
#pragma unroll
  for (int r = 0; r < 4; ++r)
#pragma unroll
    for (int e = 0; e < 4; ++e) acc[r][e] = 0.f;

  for (int kc = 0; kc < FI; kc += 32) {
    __syncthreads();
    {
      const int f = t >> 1, kb = (t & 1) * 16;
      const float* wsrc = W + (size_t)f * FI + kc + kb;
#pragma unroll
      for (int e = 0; e < 16; ++e) wt[kb + e][f] = wsrc[e];
    }
    __syncthreads();
#pragma unroll
    for (int k = 0; k < 32; ++k) {
      const float4 wv = *(const float4*)&wt[k][f4];
      float hv[4];
#pragma unroll
      for (int r = 0; r < 4; ++r) hv[r] = hs[r0 + r][kc + k];
#pragma unroll
      for (int r = 0; r < 4; ++r) {
        acc[r][0] += hv[r] * wv.x;
        acc[r][1] += hv[r] * wv.y;
        acc[r][2] += hv[r] * wv.z;
        acc[r][3] += hv[r] * wv.w;
      }
    }
  }
  const float4 bv = *(const float4*)&bias[f4];
#pragma unroll
  for (int r = 0; r < 4; ++r) {
    float4 o;
    o.x = acc[r][0] + bv.x;
    o.y = acc[r][1] + bv.y;
    o.z = acc[r][2] + bv.z;
    o.w = acc[r][3] + bv.w;
    *(float4*)&Wh[(size_t)(j0 + r0 + r) * FO + f4] = o;
  }
}

// ---------------------------------------------------------------------------
// K1b: s1/s2 scores + exp tables; block 0 also zeroes corr (k3 runs later).
//  r4[j]=(s1, e^s1, e^.2s1, 0)  c4[j]=(s2, e^s2, e^.2s2, 0)
//  r2[j]=(e^s1, e^.2s1) f32     c2h[j]=packed f16 (e^s2, e^.2s2)
// ---------------------------------------------------------------------------
__global__ __launch_bounds__(256) void k1b_sv(const float* __restrict__ Wh,
                                              const float* __restrict__ a,
                                              float4* __restrict__ r4,
                                              float4* __restrict__ c4,
                                              float2* __restrict__ r2,
                                              uint32* __restrict__ c2h,
                                              float* __restrict__ corr) {
  if (blockIdx.x == 0 && threadIdx.x < FO) corr[threadIdx.x] = 0.f;
  const int lane = threadIdx.x & 63;
  const int j = blockIdx.x * 4 + (threadIdx.x >> 6);
  const float* row = Wh + (size_t)j * FO;
  const float w0 = row[lane], w1 = row[lane + 64];
  float s1 = w0 * a[lane] + w1 * a[lane + 64];
  float s2 = w0 * a[FO + lane] + w1 * a[FO + lane + 64];
#pragma unroll
  for (int o = 32; o >= 1; o >>= 1) {
    s1 += __shfl_xor(s1, o);
    s2 += __shfl_xor(s2, o);
  }
  if (lane == 0) {
    const float e1 = expf(s1), e1a = expf(GAT_ALPHA * s1);
    const float e2 = expf(s2), e2a = expf(GAT_ALPHA * s2);
    float4 rv; rv.x = s1; rv.y = e1; rv.z = e1a; rv.w = 0.f;
    float4 cv; cv.x = s2; cv.y = e2; cv.z = e2a; cv.w = 0.f;
    r4[j] = rv;
    c4[j] = cv;
    r2[j] = make_float2(e1, e1a);
    f16x2 cp; cp.x = (_Float16)e2; cp.y = (_Float16)e2a;
    c2h[j] = __builtin_bit_cast(uint32, cp);
  }
}

// ---------------------------------------------------------------------------
// K2: single pass over adj (268 MB HBM floor): pack row-major bitmask via
// __ballot; per-column partial Z sums (sign-split so c-factor hoists).
// ---------------------------------------------------------------------------
__global__ __launch_bounds__(256) void k2_stats(const int* __restrict__ adj,
                                                const float4* __restrict__ r4,
                                                const float4* __restrict__ c4,
                                                unsigned long long* __restrict__ bits,
                                                float2* __restrict__ zpart) {
  __shared__ float4 rs[512];
  const int t = threadIdx.x;
  const int jc = blockIdx.x & 31;
  const int ic = blockIdx.x >> 5;
  const int j0 = jc * 256;
  const int i0 = ic * 512;
  for (int e = t; e < 512; e += 256) rs[e] = r4[i0 + e];
  __syncthreads();
  const int j = j0 + t;
  const float4 cj = c4[j];
  float accP = 0.f, accN = 0.f;
  const int wv = t >> 6;
  const int* ap = adj + (size_t)i0 * NN + j;
  unsigned long long* bp = bits + (size_t)i0 * (NN / 64) + (j0 >> 6) + wv;
  for (int ir = 0; ir < 512; ir += 16) {
    int av[16];
#pragma unroll
    for (int u = 0; u < 16; ++u) av[u] = ap[(ir + u) * NN];
#pragma unroll
    for (int u = 0; u < 16; ++u) {
      const float4 ri = rs[ir + u];
      const bool act = av[u] > 0;
      const unsigned long long m = __ballot(act);
      if ((t & 63) == 0) bp[(size_t)(ir + u) * (NN / 64)] = m;
      const float x = ri.x + cj.x;
      const bool pos = x >= 0.f;
      accP += (act && pos) ? ri.y : 0.f;
      accN += (act && !pos) ? ri.z : 0.f;
    }
  }
  float2 z;
  z.x = accP;
  z.y = accN;
  zpart[(size_t)ic * NN + j] = z;
}

// ---------------------------------------------------------------------------
// K3: Z_j from partials; emit Wfrag = (Wh[j][f]/Z_j) in MFMA-B-fragment-major
// layout: granule g=(kchunk*8+fb)*64+lane holds 8 f16: f=fb*16+(lane&15),
// j=kchunk*32+(lane>>4)*8+e.  Empty cols -> corr[f] (uniform softmax fix).
// ---------------------------------------------------------------------------
__global__ __launch_bounds__(256) void k3_scale(const float* __restrict__ Wh,
                                                const float4* __restrict__ c4,
                                                const float2* __restrict__ zpart,
                                                _Float16* __restrict__ Wfrag,
                                                float* __restrict__ corr) {
  __shared__ float rz[64];
  __shared__ int emp[64];
  __shared__ __align__(16) _Float16 tile[FO * 64];  // [f][64 j], 128B rows, XOR-swz
  const int t = threadIdx.x;
  const int j0 = blockIdx.x * 64;
  if (t < 64) {
    const int j = j0 + t;
    float p = 0.f, n = 0.f;
#pragma unroll
    for (int ic = 0; ic < 16; ++ic) {
      const float2 z = zpart[(size_t)ic * NN + j];
      p += z.x;
      n += z.y;
    }
    const float4 cj = c4[j];
    const float Z = cj.y * p + cj.z * n;
    rz[t] = (Z > 0.f) ? 1.f / Z : 0.f;
    emp[t] = (Z > 0.f) ? 0 : 1;
  }
  __syncthreads();
  const int f = t & 127, half = t >> 7;
  const unsigned swf = (unsigned)((f & 7) << 4);
  for (int r = half; r < 64; r += 2) {
    const float v = Wh[(size_t)(j0 + r) * FO + f];
    *(_Float16*)((char*)tile + f * 128 + (((unsigned)(r * 2)) ^ swf)) =
        (_Float16)(v * rz[r]);
    if (emp[r]) atomicAdd(&corr[f], v * (1.f / 8192.f));
  }
  __syncthreads();
#pragma unroll
  for (int q = 0; q < 4; ++q) {
    const int G = t + 256 * q;
    const int kcfb = G >> 6, gl = G & 63;
    const int kc = kcfb >> 3, fb = kcfb & 7;
    const int gf = fb * 16 + (gl & 15);
    const int jloc = kc * 32 + (gl >> 4) * 8;
    const f16x8 v = *(const f16x8*)((const char*)tile + gf * 128 +
                                    (((unsigned)(jloc * 2)) ^ ((unsigned)((gf & 7) << 4))));
    ((f16x8*)Wfrag)[(size_t)(((j0 >> 5) + kc) * 8 + fb) * 64 + gl] = v;
  }
}

// ---------------------------------------------------------------------------
// K4: partial h' = P~ @ (Wh/Z) over this block's K-range -> private partial
// buffer part[kq] (plain stores, no atomics, no zeroing needed).
//   P~[i][j] = bit(i,j) * max(e^{s1}e^{s2}, e^{.2s1}e^{.2s2})   (== exp LReLU)
// BM=64 rows, ksplit=4 (2048 cols each, 32 steps of 64). 512 thr = 8 waves
// (2 wr x 4 wc, wave tile 32r x 32f). P via swizzled LDS (conflict-free b128),
// B-frags direct global (fragment-major, coalesced), all inputs reg-prefetched.
// ---------------------------------------------------------------------------
__global__ __launch_bounds__(512, 4) void k4_main(const uchar* __restrict__ bitsB,
                                                  const float2* __restrict__ r2,
                                                  const uint32* __restrict__ c2h,
                                                  const _Float16* __restrict__ Wfrag,
                                                  float* __restrict__ part) {
  __shared__ __align__(16) _Float16 P[2][64 * 64];  // [row][64 k], 128B rows, XOR-swz
  const int t = threadIdx.x;
  const int rowtile = blockIdx.x >> 2;
  const int kq = blockIdx.x & 3;
  const int rowbase = rowtile * 64;
  const int koff = kq * 2048;

  // ---- P-gen thread ids: row pr, 8 consecutive j at jq*8
  const int pr = t >> 3, jq = t & 7;
  const float2 rr = r2[rowbase + pr];
  const uchar* bp = bitsB + (size_t)(rowbase + pr) * (NN / 8) + (koff >> 3) + jq;
  const uint32* cp = c2h + koff + jq * 8;
  char* const pdst0 = (char*)&P[0][0] + pr * 128 + (((unsigned)(jq * 16)) ^ ((unsigned)((pr & 7) << 4)));
  char* const pdst1 = (char*)&P[1][0] + pr * 128 + (((unsigned)(jq * 16)) ^ ((unsigned)((pr & 7) << 4)));

  // ---- MFMA ids
  const int lane = t & 63, wave = t >> 6;
  const int wr = wave >> 2, wc = wave & 3;
  const int kgrp = lane >> 4, l15 = lane & 15;
  const unsigned asw = (unsigned)((l15 & 7) << 4);
  const int ar0 = (wr * 32 + l15) * 128;
  const int ar1 = ar0 + 16 * 128;

  f32x4 acc00 = {0.f, 0.f, 0.f, 0.f}, acc01 = {0.f, 0.f, 0.f, 0.f};
  f32x4 acc10 = {0.f, 0.f, 0.f, 0.f}, acc11 = {0.f, 0.f, 0.f, 0.f};

  uchar mb0, mb1;
  uint32 c0a[4], c0b[4], c1a[4], c1b[4];
  f16x8 B000, B001, B010, B011, B100, B101, B110, B111;

#define LOADALL(S, MB, CA, CB, Bq00, Bq01, Bq10, Bq11)                              \
  do {                                                                              \
    MB = bp[(S) * 8];                                                               \
    const uint4 _ca = *(const uint4*)(cp + (S) * 64);                               \
    const uint4 _cb = *(const uint4*)(cp + (S) * 64 + 4);                           \
    CA[0] = _ca.x; CA[1] = _ca.y; CA[2] = _ca.z; CA[3] = _ca.w;                     \
    CB[0] = _cb.x; CB[1] = _cb.y; CB[2] = _cb.z; CB[3] = _cb.w;                     \
    const _Float16* _b = Wfrag + ((size_t)((kq * 64 + (S) * 2) * 8 + wc * 2) * 64 + lane) * 8; \
    Bq00 = *(const f16x8*)(_b);                                                     \
    Bq01 = *(const f16x8*)(_b + 512);                                               \
    Bq10 = *(const f16x8*)(_b + 4096);                                              \
    Bq11 = *(const f16x8*)(_b + 4096 + 512);                                        \
  } while (0)

#define PGEN(DST, MB, CA, CB)                                                       \
  do {                                                                              \
    union { f16x2 h[4]; f16x8 v; } U;                                               \
    _Pragma("unroll") for (int _p = 0; _p < 4; ++_p) {                              \
      const uint32 cv0 = (_p < 2) ? CA[2 * _p] : CB[2 * (_p - 2)];                  \
      const uint32 cv1 = (_p < 2) ? CA[2 * _p + 1] : CB[2 * (_p - 2) + 1];          \
      const f16x2 ch0 = __builtin_bit_cast(f16x2, cv0);                             \
      const f16x2 ch1 = __builtin_bit_cast(f16x2, cv1);                             \
      const float m0 = fmaxf(rr.x * (float)ch0.x, rr.y * (float)ch0.y);             \
      const float m1 = fmaxf(rr.x * (float)ch1.x, rr.y * (float)ch1.y);             \
      const float w0 = ((MB >> (2 * _p)) & 1) ? m0 : 0.f;                           \
      const float w1 = ((MB >> (2 * _p + 1)) & 1) ? m1 : 0.f;                       \
      U.h[_p] = __builtin_bit_cast(f16x2, __builtin_amdgcn_cvt_pkrtz(w0, w1));      \
    }                                                                               \
    *(f16x8*)(DST) = U.v;                                                           \
  } while (0)

#define DO_MFMA(BUF, Bq00, Bq01, Bq10, Bq11)                                        \
  do {                                                                              \
    const char* _Pb = (const char*)&P[BUF][0];                                      \
    const f16x8 a00 = *(const f16x8*)(_Pb + ar0 + ((((unsigned)(kgrp * 16))) ^ asw));        \
    const f16x8 a01 = *(const f16x8*)(_Pb + ar0 + (((unsigned)(64 + kgrp * 16)) ^ asw));     \
    const f16x8 a10 = *(const f16x8*)(_Pb + ar1 + ((((unsigned)(kgrp * 16))) ^ asw));        \
    const f16x8 a11 = *(const f16x8*)(_Pb + ar1 + (((unsigned)(64 + kgrp * 16)) ^ asw));     \
    acc00 = __builtin_amdgcn_mfma_f32_16x16x32_f16(a00, Bq00, acc00, 0, 0, 0);      \
    acc01 = __builtin_amdgcn_mfma_f32_16x16x32_f16(a00, Bq01, acc01, 0, 0, 0);      \
    acc10 = __builtin_amdgcn_mfma_f32_16x16x32_f16(a10, Bq00, acc10, 0, 0, 0);      \
    acc11 = __builtin_amdgcn_mfma_f32_16x16x32_f16(a10, Bq01, acc11, 0, 0, 0);      \
    acc00 = __builtin_amdgcn_mfma_f32_16x16x32_f16(a01, Bq10, acc00, 0, 0, 0);      \
    acc01 = __builtin_amdgcn_mfma_f32_16x16x32_f16(a01, Bq11, acc01, 0, 0, 0);      \
    acc10 = __builtin_amdgcn_mfma_f32_16x16x32_f16(a11, Bq10, acc10, 0, 0, 0);      \
    acc11 = __builtin_amdgcn_mfma_f32_16x16x32_f16(a11, Bq11, acc11, 0, 0, 0);      \
  } while (0)

  // ---- prologue
  LOADALL(0, mb0, c0a, c0b, B000, B001, B010, B011);
  LOADALL(1, mb1, c1a, c1b, B100, B101, B110, B111);
  PGEN(pdst0, mb0, c0a, c0b);
  __syncthreads();

  for (int s = 0; s < 32; s += 2) {
    // ---- even body: step s
    PGEN(pdst1, mb1, c1a, c1b);                       // step s+1
    DO_MFMA(0, B000, B001, B010, B011);               // step s
    if (s + 2 < 32) LOADALL(s + 2, mb0, c0a, c0b, B000, B001, B010, B011);
    __syncthreads();
    // ---- odd body: step s+1
    DO_MFMA(1, B100, B101, B110, B111);               // step s+1
    if (s + 2 < 32) PGEN(pdst0, mb0, c0a, c0b);       // step s+2
    if (s + 3 < 32) LOADALL(s + 3, mb1, c1a, c1b, B100, B101, B110, B111);
    __syncthreads();
  }

#undef LOADALL
#undef PGEN
#undef DO_MFMA

  // ---- epilogue: plain stores to this block's private partial buffer
  const int orow = rowbase + wr * 32 + kgrp * 4;
  const int ocol = wc * 32 + l15;
  float* aP = part + (size_t)kq * NN * FO + (size_t)orow * FO + ocol;
#pragma unroll
  for (int r = 0; r < 4; ++r) {
    aP[(size_t)r * FO] = acc00[r];
    aP[(size_t)r * FO + 16] = acc01[r];
    aP[(size_t)(16 + r) * FO] = acc10[r];
    aP[(size_t)(16 + r) * FO + 16] = acc11[r];
  }
}

// ---------------------------------------------------------------------------
// K5: out = elu(sum_q part[q] + corr)
// ---------------------------------------------------------------------------
__global__ __launch_bounds__(256) void k5_fin(const float* __restrict__ part,
                                              const float* __restrict__ corr,
                                              float* __restrict__ out) {
  const int idx = blockIdx.x * 256 + threadIdx.x;  // float4 index, 262144 total
  const float4 p0 = ((const float4*)part)[idx];
  const float4 p1 = ((const float4*)(part + (size_t)NN * FO))[idx];
  const float4 p2 = ((const float4*)(part + (size_t)2 * NN * FO))[idx];
  const float4 p3 = ((const float4*)(part + (size_t)3 * NN * FO))[idx];
  const float4 c = ((const float4*)corr)[idx & 31];
  float4 v;
  v.x = p0.x + p1.x + p2.x + p3.x + c.x;
  v.y = p0.y + p1.y + p2.y + p3.y + c.y;
  v.z = p0.z + p1.z + p2.z + p3.z + c.z;
  v.w = p0.w + p1.w + p2.w + p3.w + c.w;
  v.x = (v.x > 0.f) ? v.x : (expf(v.x) - 1.f);
  v.y = (v.y > 0.f) ? v.y : (expf(v.y) - 1.f);
  v.z = (v.z > 0.f) ? v.z : (expf(v.z) - 1.f);
  v.w = (v.w > 0.f) ? v.w : (expf(v.w) - 1.f);
  ((float4*)out)[idx] = v;
}

// ---------------------------------------------------------------------------
extern "C" void kernel_launch(void* const* d_in, const int* in_sizes, int n_in,
                              void* d_out, int out_size, void* d_ws, size_t ws_size,
                              hipStream_t stream) {
  const float* h = (const float*)d_in[0];
  const int* adj = (const int*)d_in[1];
  const float* W = (const float*)d_in[2];
  const float* b = (const float*)d_in[3];
  const float* a = (const float*)d_in[4];
  float* out = (float*)d_out;
  char* ws = (char*)d_ws;

  // workspace carve (32 MB total; d_ws is ~1 GB per harness poison-fill size)
  float* Wh = (float*)(ws + 0);                                   // 4 MB [k1..k3]
  _Float16* Wfrag = (_Float16*)(ws + 4194304);                    // 2 MB [k3..k4]
  unsigned long long* bits = (unsigned long long*)(ws + 6291456); // 8 MB [k2..k4]
  float2* zpart = (float2*)(ws + 14680064);                       // 1 MB [k2..k3]
  float4* r4 = (float4*)(ws + 15728640);                          // 128 KB
  float4* c4 = (float4*)(ws + 15859712);                          // 128 KB
  float2* r2 = (float2*)(ws + 15990784);                          // 64 KB
  uint32* c2h = (uint32*)(ws + 16056320);                         // 32 KB
  float* corr = (float*)(ws + 16089088);                          // 512 B
  float* part = (float*)(ws + 16777216);                          // 16 MB [k4..k5]

  k1_wh<<<NN / 32, 256, 0, stream>>>(h, W, b, Wh);
  k1b_sv<<<NN / 4, 256, 0, stream>>>(Wh, a, r4, c4, r2, c2h, corr);
  k2_stats<<<512, 256, 0, stream>>>(adj, r4, c4, bits, zpart);
  k3_scale<<<NN / 64, 256, 0, stream>>>(Wh, c4, zpart, Wfrag, corr);
  k4_main<<<512, 512, 0, stream>>>((const uchar*)bits, r2, c2h, Wfrag, part);
  k5_fin<<<(NN * FO / 4) / 256, 256, 0, stream>>>(part, corr, out);
}

// Round 6
// 127.591 us; speedup vs baseline: 2.1953x; 1.1793x over previous
//
#include <hip/hip_runtime.h>

#define NN 8192
#define FI 256
#define FO 128
#define GAT_ALPHA 0.2f

typedef _Float16 f16x8 __attribute__((ext_vector_type(8)));
typedef _Float16 f16x2 __attribute__((ext_vector_type(2)));
typedef float f32x4 __attribute__((ext_vector_type(4)));
typedef unsigned char uchar;
typedef unsigned int uint32;

// ---------------------------------------------------------------------------
// K1: Wh[j][f] = sum_k h[j][k] * W[f][k] + b[f]   (fp32, LDS-tiled)
// ---------------------------------------------------------------------------
__global__ __launch_bounds__(256) void k1_wh(const float* __restrict__ h,
                                             const float* __restrict__ W,
                                             const float* __restrict__ bias,
                                             float* __restrict__ Wh) {
  __shared__ float hs[32][FI + 1];
  __shared__ float wt[32][FO];
  const int t = threadIdx.x;
  const int j0 = blockIdx.x * 32;
  {
    const int row = t >> 3, c0 = (t & 7) * 32;
    const float* src = h + (size_t)(j0 + row) * FI + c0;
#pragma unroll
    for (int e = 0; e < 8; ++e) {
      float4 v = *(const float4*)(src + 4 * e);
      hs[row][c0 + 4 * e + 0] = v.x;
      hs[row][c0 + 4 * e + 1] = v.y;
      hs[row][c0 + 4 * e + 2] = v.z;
      hs[row][c0 + 4 * e + 3] = v.w;
    }
  }
  const int f4 = (t & 31) * 4;
  const int r0 = (t >> 5) * 4;
  float acc[4][4];
#pragma unroll
  for (int r = 0; r < 4; ++r)
#pragma unroll
    for (int e = 0; e < 4; ++e) acc[r][e] = 0.f;

  for (int kc = 0; kc < FI; kc += 32) {
    __syncthreads();
    {
      const int f = t >> 1, kb = (t & 1) * 16;
      const float* wsrc = W + (size_t)f * FI + kc + kb;
#pragma unroll
      for (int e = 0; e < 16; ++e) wt[kb + e][f] = wsrc[e];
    }
    __syncthreads();
#pragma unroll
    for (int k = 0; k < 32; ++k) {
      const float4 wv = *(const float4*)&wt[k][f4];
      float hv[4];
#pragma unroll
      for (int r = 0; r < 4; ++r) hv[r] = hs[r0 + r][kc + k];
#pragma unroll
      for (int r = 0; r < 4; ++r) {
        acc[r][0] += hv[r] * wv.x;
        acc[r][1] += hv[r] * wv.y;
        acc[r][2] += hv[r] * wv.z;
        acc[r][3] += hv[r] * wv.w;
      }
    }
  }
  const float4 bv = *(const float4*)&bias[f4];
#pragma unroll
  for (int r = 0; r < 4; ++r) {
    float4 o;
    o.x = acc[r][0] + bv.x;
    o.y = acc[r][1] + bv.y;
    o.z = acc[r][2] + bv.z;
    o.w = acc[r][3] + bv.w;
    *(float4*)&Wh[(size_t)(j0 + r0 + r) * FO + f4] = o;
  }
}

// ---------------------------------------------------------------------------
// K1b: s1/s2 scores + exp tables; block 0 also zeroes corr (k3 runs later).
//  r4[j]=(s1, e^s1, e^.2s1, 0)  c4[j]=(s2, e^s2, e^.2s2, 0)
//  r2[j]=(e^s1, e^.2s1) f32     c2h[j]=packed f16 (e^s2, e^.2s2)   s2x[j]=s2
// ---------------------------------------------------------------------------
__global__ __launch_bounds__(256) void k1b_sv(const float* __restrict__ Wh,
                                              const float* __restrict__ a,
                                              float4* __restrict__ r4,
                                              float4* __restrict__ c4,
                                              float2* __restrict__ r2,
                                              uint32* __restrict__ c2h,
                                              float* __restrict__ s2x,
                                              float* __restrict__ corr) {
  if (blockIdx.x == 0 && threadIdx.x < FO) corr[threadIdx.x] = 0.f;
  const int lane = threadIdx.x & 63;
  const int j = blockIdx.x * 4 + (threadIdx.x >> 6);
  const float* row = Wh + (size_t)j * FO;
  const float w0 = row[lane], w1 = row[lane + 64];
  float s1 = w0 * a[lane] + w1 * a[lane + 64];
  float s2 = w0 * a[FO + lane] + w1 * a[FO + lane + 64];
#pragma unroll
  for (int o = 32; o >= 1; o >>= 1) {
    s1 += __shfl_xor(s1, o);
    s2 += __shfl_xor(s2, o);
  }
  if (lane == 0) {
    const float e1 = expf(s1), e1a = expf(GAT_ALPHA * s1);
    const float e2 = expf(s2), e2a = expf(GAT_ALPHA * s2);
    float4 rv; rv.x = s1; rv.y = e1; rv.z = e1a; rv.w = 0.f;
    float4 cv; cv.x = s2; cv.y = e2; cv.z = e2a; cv.w = 0.f;
    r4[j] = rv;
    c4[j] = cv;
    r2[j] = make_float2(e1, e1a);
    f16x2 cp; cp.x = (_Float16)e2; cp.y = (_Float16)e2a;
    c2h[j] = __builtin_bit_cast(uint32, cp);
    s2x[j] = s2;
  }
}

// ---------------------------------------------------------------------------
// K2: single pass over adj (268 MB HBM floor). Each thread owns 8 consecutive
// j (2x int4 = 32 B/lane, 2 KB contiguous per wave-row), packs the 8 activity
// bits into one byte (no ballot), coalesced byte stores; 8 accP/accN register
// accumulators. Grid: 4 j-chunks (2048) x 128 i-chunks (64 rows).
// ---------------------------------------------------------------------------
__global__ __launch_bounds__(256) void k2_stats(const int* __restrict__ adj,
                                                const float4* __restrict__ r4,
                                                const float* __restrict__ s2x,
                                                uchar* __restrict__ bitsB,
                                                float2* __restrict__ zpart) {
  __shared__ float4 rs[64];
  const int t = threadIdx.x;
  const int jc = blockIdx.x & 3;
  const int ic = blockIdx.x >> 2;
  const int i0 = ic * 64;
  const int j0 = jc * 2048 + t * 8;
  if (t < 64) rs[t] = r4[i0 + t];
  const float4 ca = *(const float4*)(s2x + j0);
  const float4 cb = *(const float4*)(s2x + j0 + 4);
  const float cx[8] = {ca.x, ca.y, ca.z, ca.w, cb.x, cb.y, cb.z, cb.w};
  float accP[8], accN[8];
#pragma unroll
  for (int e = 0; e < 8; ++e) { accP[e] = 0.f; accN[e] = 0.f; }
  __syncthreads();
  const int4* ap = (const int4*)(adj + (size_t)i0 * NN + j0);
  uchar* bp = bitsB + (size_t)i0 * (NN / 8) + jc * 256 + t;
  for (int ir = 0; ir < 64; ir += 8) {
    int4 av[8][2];
#pragma unroll
    for (int u = 0; u < 8; ++u) {
      av[u][0] = ap[(size_t)(ir + u) * (NN / 4)];
      av[u][1] = ap[(size_t)(ir + u) * (NN / 4) + 1];
    }
#pragma unroll
    for (int u = 0; u < 8; ++u) {
      const float4 ri = rs[ir + u];
      const int aa[8] = {av[u][0].x, av[u][0].y, av[u][0].z, av[u][0].w,
                         av[u][1].x, av[u][1].y, av[u][1].z, av[u][1].w};
      uint32 byte = 0;
#pragma unroll
      for (int e = 0; e < 8; ++e) {
        const bool act = aa[e] > 0;
        byte |= act ? (1u << e) : 0u;
        const bool pos = (ri.x + cx[e]) >= 0.f;
        accP[e] += (act && pos) ? ri.y : 0.f;
        accN[e] += (act && !pos) ? ri.z : 0.f;
      }
      bp[(size_t)(ir + u) * (NN / 8)] = (uchar)byte;
    }
  }
  float2* zp = zpart + (size_t)ic * NN + j0;
#pragma unroll
  for (int e = 0; e < 8; ++e) zp[e] = make_float2(accP[e], accN[e]);
}

// ---------------------------------------------------------------------------
// K3: Z_j from 128 partials (4-way parallel + LDS reduce); emit Wfrag =
// (Wh[j][f]/Z_j) in MFMA-B-fragment-major layout: granule g=(kchunk*8+fb)*64
// +lane holds 8 f16: f=fb*16+(lane&15), j=kchunk*32+(lane>>4)*8+e.
// Empty cols -> corr[f] (uniform softmax fix).
// ---------------------------------------------------------------------------
__global__ __launch_bounds__(256) void k3_scale(const float* __restrict__ Wh,
                                                const float4* __restrict__ c4,
                                                const float2* __restrict__ zpart,
                                                _Float16* __restrict__ Wfrag,
                                                float* __restrict__ corr) {
  __shared__ float rz[64];
  __shared__ int emp[64];
  __shared__ float2 psum[256];
  __shared__ __align__(16) _Float16 tile[FO * 64];  // [f][64 j], 128B rows, XOR-swz
  const int t = threadIdx.x;
  const int j0 = blockIdx.x * 64;
  {
    const int jl = t & 63, q = t >> 6;
    float p = 0.f, n = 0.f;
    for (int ic = q * 32; ic < q * 32 + 32; ++ic) {
      const float2 z = zpart[(size_t)ic * NN + j0 + jl];
      p += z.x;
      n += z.y;
    }
    psum[t] = make_float2(p, n);
  }
  __syncthreads();
  if (t < 64) {
    const float p = psum[t].x + psum[64 + t].x + psum[128 + t].x + psum[192 + t].x;
    const float n = psum[t].y + psum[64 + t].y + psum[128 + t].y + psum[192 + t].y;
    const float4 cj = c4[j0 + t];
    const float Z = cj.y * p + cj.z * n;
    rz[t] = (Z > 0.f) ? 1.f / Z : 0.f;
    emp[t] = (Z > 0.f) ? 0 : 1;
  }
  __syncthreads();
  const int f = t & 127, half = t >> 7;
  const unsigned swf = (unsigned)((f & 7) << 4);
  for (int r = half; r < 64; r += 2) {
    const float v = Wh[(size_t)(j0 + r) * FO + f];
    *(_Float16*)((char*)tile + f * 128 + (((unsigned)(r * 2)) ^ swf)) =
        (_Float16)(v * rz[r]);
    if (emp[r]) atomicAdd(&corr[f], v * (1.f / 8192.f));
  }
  __syncthreads();
#pragma unroll
  for (int q = 0; q < 4; ++q) {
    const int G = t + 256 * q;
    const int kcfb = G >> 6, gl = G & 63;
    const int kc = kcfb >> 3, fb = kcfb & 7;
    const int gf = fb * 16 + (gl & 15);
    const int jloc = kc * 32 + (gl >> 4) * 8;
    const f16x8 v = *(const f16x8*)((const char*)tile + gf * 128 +
                                    (((unsigned)(jloc * 2)) ^ ((unsigned)((gf & 7) << 4))));
    ((f16x8*)Wfrag)[(size_t)(((j0 >> 5) + kc) * 8 + fb) * 64 + gl] = v;
  }
}

// ---------------------------------------------------------------------------
// K4: partial h' = P~ @ (Wh/Z) over this block's K-range -> private partial
// buffer part[kq] (plain stores, no atomics, no zeroing needed).
//   P~[i][j] = bit(i,j) * max(e^{s1}e^{s2}, e^{.2s1}e^{.2s2})   (== exp LReLU)
// BM=64 rows, ksplit=4 (2048 cols each, 32 steps of 64). 512 thr = 8 waves
// (2 wr x 4 wc, wave tile 32r x 32f). P via swizzled LDS (conflict-free b128),
// B-frags direct global (fragment-major, coalesced), all inputs reg-prefetched.
// ---------------------------------------------------------------------------
__global__ __launch_bounds__(512, 4) void k4_main(const uchar* __restrict__ bitsB,
                                                  const float2* __restrict__ r2,
                                                  const uint32* __restrict__ c2h,
                                                  const _Float16* __restrict__ Wfrag,
                                                  float* __restrict__ part) {
  __shared__ __align__(16) _Float16 P[2][64 * 64];  // [row][64 k], 128B rows, XOR-swz
  const int t = threadIdx.x;
  const int rowtile = blockIdx.x >> 2;
  const int kq = blockIdx.x & 3;
  const int rowbase = rowtile * 64;
  const int koff = kq * 2048;

  // ---- P-gen thread ids: row pr, 8 consecutive j at jq*8
  const int pr = t >> 3, jq = t & 7;
  const float2 rr = r2[rowbase + pr];
  const uchar* bp = bitsB + (size_t)(rowbase + pr) * (NN / 8) + (koff >> 3) + jq;
  const uint32* cp = c2h + koff + jq * 8;
  char* const pdst0 = (char*)&P[0][0] + pr * 128 + (((unsigned)(jq * 16)) ^ ((unsigned)((pr & 7) << 4)));
  char* const pdst1 = (char*)&P[1][0] + pr * 128 + (((unsigned)(jq * 16)) ^ ((unsigned)((pr & 7) << 4)));

  // ---- MFMA ids
  const int lane = t & 63, wave = t >> 6;
  const int wr = wave >> 2, wc = wave & 3;
  const int kgrp = lane >> 4, l15 = lane & 15;
  const unsigned asw = (unsigned)((l15 & 7) << 4);
  const int ar0 = (wr * 32 + l15) * 128;
  const int ar1 = ar0 + 16 * 128;

  f32x4 acc00 = {0.f, 0.f, 0.f, 0.f}, acc01 = {0.f, 0.f, 0.f, 0.f};
  f32x4 acc10 = {0.f, 0.f, 0.f, 0.f}, acc11 = {0.f, 0.f, 0.f, 0.f};

  uchar mb0, mb1;
  uint32 c0a[4], c0b[4], c1a[4], c1b[4];
  f16x8 B000, B001, B010, B011, B100, B101, B110, B111;

#define LOADALL(S, MB, CA, CB, Bq00, Bq01, Bq10, Bq11)                              \
  do {                                                                              \
    MB = bp[(S) * 8];                                                               \
    const uint4 _ca = *(const uint4*)(cp + (S) * 64);                               \
    const uint4 _cb = *(const uint4*)(cp + (S) * 64 + 4);                           \
    CA[0] = _ca.x; CA[1] = _ca.y; CA[2] = _ca.z; CA[3] = _ca.w;                     \
    CB[0] = _cb.x; CB[1] = _cb.y; CB[2] = _cb.z; CB[3] = _cb.w;                     \
    const _Float16* _b = Wfrag + ((size_t)((kq * 64 + (S) * 2) * 8 + wc * 2) * 64 + lane) * 8; \
    Bq00 = *(const f16x8*)(_b);                                                     \
    Bq01 = *(const f16x8*)(_b + 512);                                               \
    Bq10 = *(const f16x8*)(_b + 4096);                                              \
    Bq11 = *(const f16x8*)(_b + 4096 + 512);                                        \
  } while (0)

#define PGEN(DST, MB, CA, CB)                                                       \
  do {                                                                              \
    union { f16x2 h[4]; f16x8 v; } U;                                               \
    _Pragma("unroll") for (int _p = 0; _p < 4; ++_p) {                              \
      const uint32 cv0 = (_p < 2) ? CA[2 * _p] : CB[2 * (_p - 2)];                  \
      const uint32 cv1 = (_p < 2) ? CA[2 * _p + 1] : CB[2 * (_p - 2) + 1];          \
      const f16x2 ch0 = __builtin_bit_cast(f16x2, cv0);                             \
      const f16x2 ch1 = __builtin_bit_cast(f16x2, cv1);                             \
      const float m0 = fmaxf(rr.x * (float)ch0.x, rr.y * (float)ch0.y);             \
      const float m1 = fmaxf(rr.x * (float)ch1.x, rr.y * (float)ch1.y);             \
      const float w0 = ((MB >> (2 * _p)) & 1) ? m0 : 0.f;                           \
      const float w1 = ((MB >> (2 * _p + 1)) & 1) ? m1 : 0.f;                       \
      U.h[_p] = __builtin_bit_cast(f16x2, __builtin_amdgcn_cvt_pkrtz(w0, w1));      \
    }                                                                               \
    *(f16x8*)(DST) = U.v;                                                           \
  } while (0)

#define DO_MFMA(BUF, Bq00, Bq01, Bq10, Bq11)                                        \
  do {                                                                              \
    const char* _Pb = (const char*)&P[BUF][0];                                      \
    const f16x8 a00 = *(const f16x8*)(_Pb + ar0 + ((((unsigned)(kgrp * 16))) ^ asw));        \
    const f16x8 a01 = *(const f16x8*)(_Pb + ar0 + (((unsigned)(64 + kgrp * 16)) ^ asw));     \
    const f16x8 a10 = *(const f16x8*)(_Pb + ar1 + ((((unsigned)(kgrp * 16))) ^ asw));        \
    const f16x8 a11 = *(const f16x8*)(_Pb + ar1 + (((unsigned)(64 + kgrp * 16)) ^ asw));     \
    acc00 = __builtin_amdgcn_mfma_f32_16x16x32_f16(a00, Bq00, acc00, 0, 0, 0);      \
    acc01 = __builtin_amdgcn_mfma_f32_16x16x32_f16(a00, Bq01, acc01, 0, 0, 0);      \
    acc10 = __builtin_amdgcn_mfma_f32_16x16x32_f16(a10, Bq00, acc10, 0, 0, 0);      \
    acc11 = __builtin_amdgcn_mfma_f32_16x16x32_f16(a10, Bq01, acc11, 0, 0, 0);      \
    acc00 = __builtin_amdgcn_mfma_f32_16x16x32_f16(a01, Bq10, acc00, 0, 0, 0);      \
    acc01 = __builtin_amdgcn_mfma_f32_16x16x32_f16(a01, Bq11, acc01, 0, 0, 0);      \
    acc10 = __builtin_amdgcn_mfma_f32_16x16x32_f16(a11, Bq10, acc10, 0, 0, 0);      \
    acc11 = __builtin_amdgcn_mfma_f32_16x16x32_f16(a11, Bq11, acc11, 0, 0, 0);      \
  } while (0)

  // ---- prologue
  LOADALL(0, mb0, c0a, c0b, B000, B001, B010, B011);
  LOADALL(1, mb1, c1a, c1b, B100, B101, B110, B111);
  PGEN(pdst0, mb0, c0a, c0b);
  __syncthreads();

  for (int s = 0; s < 32; s += 2) {
    // ---- even body: step s
    PGEN(pdst1, mb1, c1a, c1b);                       // step s+1
    DO_MFMA(0, B000, B001, B010, B011);               // step s
    if (s + 2 < 32) LOADALL(s + 2, mb0, c0a, c0b, B000, B001, B010, B011);
    __syncthreads();
    // ---- odd body: step s+1
    DO_MFMA(1, B100, B101, B110, B111);               // step s+1
    if (s + 2 < 32) PGEN(pdst0, mb0, c0a, c0b);       // step s+2
    if (s + 3 < 32) LOADALL(s + 3, mb1, c1a, c1b, B100, B101, B110, B111);
    __syncthreads();
  }

#undef LOADALL
#undef PGEN
#undef DO_MFMA

  // ---- epilogue: plain stores to this block's private partial buffer
  const int orow = rowbase + wr * 32 + kgrp * 4;
  const int ocol = wc * 32 + l15;
  float* aP = part + (size_t)kq * NN * FO + (size_t)orow * FO + ocol;
#pragma unroll
  for (int r = 0; r < 4; ++r) {
    aP[(size_t)r * FO] = acc00[r];
    aP[(size_t)r * FO + 16] = acc01[r];
    aP[(size_t)(16 + r) * FO] = acc10[r];
    aP[(size_t)(16 + r) * FO + 16] = acc11[r];
  }
}

// ---------------------------------------------------------------------------
// K5: out = elu(sum_q part[q] + corr)
// ---------------------------------------------------------------------------
__global__ __launch_bounds__(256) void k5_fin(const float* __restrict__ part,
                                              const float* __restrict__ corr,
                                              float* __restrict__ out) {
  const int idx = blockIdx.x * 256 + threadIdx.x;  // float4 index, 262144 total
  const float4 p0 = ((const float4*)part)[idx];
  const float4 p1 = ((const float4*)(part + (size_t)NN * FO))[idx];
  const float4 p2 = ((const float4*)(part + (size_t)2 * NN * FO))[idx];
  const float4 p3 = ((const float4*)(part + (size_t)3 * NN * FO))[idx];
  const float4 c = ((const float4*)corr)[idx & 31];
  float4 v;
  v.x = p0.x + p1.x + p2.x + p3.x + c.x;
  v.y = p0.y + p1.y + p2.y + p3.y + c.y;
  v.z = p0.z + p1.z + p2.z + p3.z + c.z;
  v.w = p0.w + p1.w + p2.w + p3.w + c.w;
  v.x = (v.x > 0.f) ? v.x : (expf(v.x) - 1.f);
  v.y = (v.y > 0.f) ? v.y : (expf(v.y) - 1.f);
  v.z = (v.z > 0.f) ? v.z : (expf(v.z) - 1.f);
  v.w = (v.w > 0.f) ? v.w : (expf(v.w) - 1.f);
  ((float4*)out)[idx] = v;
}

// ---------------------------------------------------------------------------
extern "C" void kernel_launch(void* const* d_in, const int* in_sizes, int n_in,
                              void* d_out, int out_size, void* d_ws, size_t ws_size,
                              hipStream_t stream) {
  const float* h = (const float*)d_in[0];
  const int* adj = (const int*)d_in[1];
  const float* W = (const float*)d_in[2];
  const float* b = (const float*)d_in[3];
  const float* a = (const float*)d_in[4];
  float* out = (float*)d_out;
  char* ws = (char*)d_ws;

  // workspace carve (~39 MB total; d_ws is ~1 GB per harness poison-fill size)
  float* Wh = (float*)(ws + 0);                                   // 4 MB  [k1..k3]
  _Float16* Wfrag = (_Float16*)(ws + 0x400000);                   // 2 MB  [k3..k4]
  uchar* bits = (uchar*)(ws + 0x600000);                          // 8 MB  [k2..k4]
  float2* zpart = (float2*)(ws + 0xE00000);                       // 8 MB  [k2..k3]
  float4* r4 = (float4*)(ws + 0x1600000);                         // 128 KB
  float4* c4 = (float4*)(ws + 0x1620000);                         // 128 KB
  float2* r2 = (float2*)(ws + 0x1640000);                         // 64 KB
  uint32* c2h = (uint32*)(ws + 0x1650000);                        // 32 KB
  float* s2x = (float*)(ws + 0x1658000);                          // 32 KB
  float* corr = (float*)(ws + 0x1660000);                         // 512 B
  float* part = (float*)(ws + 0x1700000);                         // 16 MB [k4..k5]

  k1_wh<<<NN / 32, 256, 0, stream>>>(h, W, b, Wh);
  k1b_sv<<<NN / 4, 256, 0, stream>>>(Wh, a, r4, c4, r2, c2h, s2x, corr);
  k2_stats<<<512, 256, 0, stream>>>(adj, r4, s2x, bits, zpart);
  k3_scale<<<NN / 64, 256, 0, stream>>>(Wh, c4, zpart, Wfrag, corr);
  k4_main<<<512, 512, 0, stream>>>(bits, r2, c2h, Wfrag, part);
  k5_fin<<<(NN * FO / 4) / 256, 256, 0, stream>>>(part, corr, out);
}

// Round 7
// 127.528 us; speedup vs baseline: 2.1964x; 1.0005x over previous
//
#include <hip/hip_runtime.h>

#define NN 8192
#define FI 256
#define FO 128
#define GAT_ALPHA 0.2f

typedef _Float16 f16x8 __attribute__((ext_vector_type(8)));
typedef _Float16 f16x2 __attribute__((ext_vector_type(2)));
typedef float f32x4 __attribute__((ext_vector_type(4)));
typedef unsigned char uchar;
typedef unsigned int uint32;

// ---------------------------------------------------------------------------
// K1: Wh[j][f] = sum_k h[j][k] * W[f][k] + b[f]   (fp32, LDS-tiled)
// ---------------------------------------------------------------------------
__global__ __launch_bounds__(256) void k1_wh(const float* __restrict__ h,
                                             const float* __restrict__ W,
                                             const float* __restrict__ bias,
                                             float* __restrict__ Wh) {
  __shared__ float hs[32][FI + 1];
  __shared__ float wt[32][FO];
  const int t = threadIdx.x;
  const int j0 = blockIdx.x * 32;
  {
    const int row = t >> 3, c0 = (t & 7) * 32;
    const float* src = h + (size_t)(j0 + row) * FI + c0;
#pragma unroll
    for (int e = 0; e < 8; ++e) {
      float4 v = *(const float4*)(src + 4 * e);
      hs[row][c0 + 4 * e + 0] = v.x;
      hs[row][c0 + 4 * e + 1] = v.y;
      hs[row][c0 + 4 * e + 2] = v.z;
      hs[row][c0 + 4 * e + 3] = v.w;
    }
  }
  const int f4 = (t & 31) * 4;
  const int r0 = (t >> 5) * 4;
  float acc[4][4];
#pragma unroll
  for (int r = 0; r < 4; ++r)
#pragma unroll
    for (int e = 0; e < 4; ++e) acc[r][e] = 0.f;

  for (int kc = 0; kc < FI; kc += 32) {
    __syncthreads();
    {
      const int f = t >> 1, kb = (t & 1) * 16;
      const float* wsrc = W + (size_t)f * FI + kc + kb;
#pragma unroll
      for (int e = 0; e < 16; ++e) wt[kb + e][f] = wsrc[e];
    }
    __syncthreads();
#pragma unroll
    for (int k = 0; k < 32; ++k) {
      const float4 wv = *(const float4*)&wt[k][f4];
      float hv[4];
#pragma unroll
      for (int r = 0; r < 4; ++r) hv[r] = hs[r0 + r][kc + k];
#pragma unroll
      for (int r = 0; r < 4; ++r) {
        acc[r][0] += hv[r] * wv.x;
        acc[r][1] += hv[r] * wv.y;
        acc[r][2] += hv[r] * wv.z;
        acc[r][3] += hv[r] * wv.w;
      }
    }
  }
  const float4 bv = *(const float4*)&bias[f4];
#pragma unroll
  for (int r = 0; r < 4; ++r) {
    float4 o;
    o.x = acc[r][0] + bv.x;
    o.y = acc[r][1] + bv.y;
    o.z = acc[r][2] + bv.z;
    o.w = acc[r][3] + bv.w;
    *(float4*)&Wh[(size_t)(j0 + r0 + r) * FO + f4] = o;
  }
}

// ---------------------------------------------------------------------------
// K1b: s1/s2 scores + exp tables; block 0 also zeroes corr (k3 runs later).
//  r4[j]=(s1, e^s1, e^.2s1, 0)  c4[j]=(s2, e^s2, e^.2s2, 0)
//  r2[j]=(e^s1, e^.2s1) f32     c2h[j]=packed f16 (e^s2, e^.2s2)   s2x[j]=s2
// ---------------------------------------------------------------------------
__global__ __launch_bounds__(256) void k1b_sv(const float* __restrict__ Wh,
                                              const float* __restrict__ a,
                                              float4* __restrict__ r4,
                                              float4* __restrict__ c4,
                                              float2* __restrict__ r2,
                                              uint32* __restrict__ c2h,
                                              float* __restrict__ s2x,
                                              float* __restrict__ corr) {
  if (blockIdx.x == 0 && threadIdx.x < FO) corr[threadIdx.x] = 0.f;
  const int lane = threadIdx.x & 63;
  const int j = blockIdx.x * 4 + (threadIdx.x >> 6);
  const float* row = Wh + (size_t)j * FO;
  const float w0 = row[lane], w1 = row[lane + 64];
  float s1 = w0 * a[lane] + w1 * a[lane + 64];
  float s2 = w0 * a[FO + lane] + w1 * a[FO + lane + 64];
#pragma unroll
  for (int o = 32; o >= 1; o >>= 1) {
    s1 += __shfl_xor(s1, o);
    s2 += __shfl_xor(s2, o);
  }
  if (lane == 0) {
    const float e1 = expf(s1), e1a = expf(GAT_ALPHA * s1);
    const float e2 = expf(s2), e2a = expf(GAT_ALPHA * s2);
    float4 rv; rv.x = s1; rv.y = e1; rv.z = e1a; rv.w = 0.f;
    float4 cv; cv.x = s2; cv.y = e2; cv.z = e2a; cv.w = 0.f;
    r4[j] = rv;
    c4[j] = cv;
    r2[j] = make_float2(e1, e1a);
    f16x2 cp; cp.x = (_Float16)e2; cp.y = (_Float16)e2a;
    c2h[j] = __builtin_bit_cast(uint32, cp);
    s2x[j] = s2;
  }
}

// ---------------------------------------------------------------------------
// K2: single pass over adj (268 MB HBM floor). Each thread owns 8 consecutive
// j (2x int4 = 32 B/lane, 2 KB contiguous per wave-row), packs the 8 activity
// bits into one byte (no ballot), coalesced byte stores; 8 accP/accN register
// accumulators. Grid: 4 j-chunks (2048) x 128 i-chunks (64 rows).
// ---------------------------------------------------------------------------
__global__ __launch_bounds__(256) void k2_stats(const int* __restrict__ adj,
                                                const float4* __restrict__ r4,
                                                const float* __restrict__ s2x,
                                                uchar* __restrict__ bitsB,
                                                float2* __restrict__ zpart) {
  __shared__ float4 rs[64];
  const int t = threadIdx.x;
  const int jc = blockIdx.x & 3;
  const int ic = blockIdx.x >> 2;
  const int i0 = ic * 64;
  const int j0 = jc * 2048 + t * 8;
  if (t < 64) rs[t] = r4[i0 + t];
  const float4 ca = *(const float4*)(s2x + j0);
  const float4 cb = *(const float4*)(s2x + j0 + 4);
  const float cx[8] = {ca.x, ca.y, ca.z, ca.w, cb.x, cb.y, cb.z, cb.w};
  float accP[8], accN[8];
#pragma unroll
  for (int e = 0; e < 8; ++e) { accP[e] = 0.f; accN[e] = 0.f; }
  __syncthreads();
  const int4* ap = (const int4*)(adj + (size_t)i0 * NN + j0);
  uchar* bp = bitsB + (size_t)i0 * (NN / 8) + jc * 256 + t;
  for (int ir = 0; ir < 64; ir += 8) {
    int4 av[8][2];
#pragma unroll
    for (int u = 0; u < 8; ++u) {
      av[u][0] = ap[(size_t)(ir + u) * (NN / 4)];
      av[u][1] = ap[(size_t)(ir + u) * (NN / 4) + 1];
    }
#pragma unroll
    for (int u = 0; u < 8; ++u) {
      const float4 ri = rs[ir + u];
      const int aa[8] = {av[u][0].x, av[u][0].y, av[u][0].z, av[u][0].w,
                         av[u][1].x, av[u][1].y, av[u][1].z, av[u][1].w};
      uint32 byte = 0;
#pragma unroll
      for (int e = 0; e < 8; ++e) {
        const bool act = aa[e] > 0;
        byte |= act ? (1u << e) : 0u;
        const bool pos = (ri.x + cx[e]) >= 0.f;
        accP[e] += (act && pos) ? ri.y : 0.f;
        accN[e] += (act && !pos) ? ri.z : 0.f;
      }
      bp[(size_t)(ir + u) * (NN / 8)] = (uchar)byte;
    }
  }
  float2* zp = zpart + (size_t)ic * NN + j0;
#pragma unroll
  for (int e = 0; e < 8; ++e) zp[e] = make_float2(accP[e], accN[e]);
}

// ---------------------------------------------------------------------------
// K3: Z_j from 128 partials (4-way parallel + LDS reduce); emit Wfrag =
// (Wh[j][f]/Z_j) in MFMA-B-fragment-major layout: granule g=(kchunk*8+fb)*64
// +lane holds 8 f16: f=fb*16+(lane&15), j=kchunk*32+(lane>>4)*8+e.
// Empty cols -> corr[f] (uniform softmax fix).
// ---------------------------------------------------------------------------
__global__ __launch_bounds__(256) void k3_scale(const float* __restrict__ Wh,
                                                const float4* __restrict__ c4,
                                                const float2* __restrict__ zpart,
                                                _Float16* __restrict__ Wfrag,
                                                float* __restrict__ corr) {
  __shared__ float rz[64];
  __shared__ int emp[64];
  __shared__ float2 psum[256];
  __shared__ __align__(16) _Float16 tile[FO * 64];  // [f][64 j], 128B rows, XOR-swz
  const int t = threadIdx.x;
  const int j0 = blockIdx.x * 64;
  {
    const int jl = t & 63, q = t >> 6;
    float p = 0.f, n = 0.f;
    for (int ic = q * 32; ic < q * 32 + 32; ++ic) {
      const float2 z = zpart[(size_t)ic * NN + j0 + jl];
      p += z.x;
      n += z.y;
    }
    psum[t] = make_float2(p, n);
  }
  __syncthreads();
  if (t < 64) {
    const float p = psum[t].x + psum[64 + t].x + psum[128 + t].x + psum[192 + t].x;
    const float n = psum[t].y + psum[64 + t].y + psum[128 + t].y + psum[192 + t].y;
    const float4 cj = c4[j0 + t];
    const float Z = cj.y * p + cj.z * n;
    rz[t] = (Z > 0.f) ? 1.f / Z : 0.f;
    emp[t] = (Z > 0.f) ? 0 : 1;
  }
  __syncthreads();
  const int f = t & 127, half = t >> 7;
  const unsigned swf = (unsigned)((f & 7) << 4);
  for (int r = half; r < 64; r += 2) {
    const float v = Wh[(size_t)(j0 + r) * FO + f];
    *(_Float16*)((char*)tile + f * 128 + (((unsigned)(r * 2)) ^ swf)) =
        (_Float16)(v * rz[r]);
    if (emp[r]) atomicAdd(&corr[f], v * (1.f / 8192.f));
  }
  __syncthreads();
#pragma unroll
  for (int q = 0; q < 4; ++q) {
    const int G = t + 256 * q;
    const int kcfb = G >> 6, gl = G & 63;
    const int kc = kcfb >> 3, fb = kcfb & 7;
    const int gf = fb * 16 + (gl & 15);
    const int jloc = kc * 32 + (gl >> 4) * 8;
    const f16x8 v = *(const f16x8*)((const char*)tile + gf * 128 +
                                    (((unsigned)(jloc * 2)) ^ ((unsigned)((gf & 7) << 4))));
    ((f16x8*)Wfrag)[(size_t)(((j0 >> 5) + kc) * 8 + fb) * 64 + gl] = v;
  }
}

// ---------------------------------------------------------------------------
// K4: partial h' = P~ @ (Wh/Z) over this block's K-range -> private partial
// buffer part[kq] (plain stores, no atomics, no zeroing needed).
//   P~[i][j] = bit(i,j) * max(e^{s1}e^{s2}, e^{.2s1}e^{.2s2})   (== exp LReLU)
// BM=64 rows, ksplit=4 (2048 cols each, 32 steps of 64). 512 thr = 8 waves
// (2 wr x 4 wc, wave tile 32r x 32f). P via swizzled LDS (conflict-free b128),
// B-frags direct global (fragment-major, coalesced), all inputs reg-prefetched
// 2 steps ahead. T4: barriers drain ONLY lgkmcnt (ds_writes) -- global
// prefetches stay in flight across barriers (use-site vmcnt waits hide them).
// T5: setprio around the MFMA cluster.
// ---------------------------------------------------------------------------
#define BARRIER_LDS()                                          \
  do {                                                         \
    __builtin_amdgcn_sched_barrier(0);                         \
    asm volatile("s_waitcnt lgkmcnt(0)" ::: "memory");         \
    __builtin_amdgcn_s_barrier();                              \
    __builtin_amdgcn_sched_barrier(0);                         \
  } while (0)

__global__ __launch_bounds__(512, 4) void k4_main(const uchar* __restrict__ bitsB,
                                                  const float2* __restrict__ r2,
                                                  const uint32* __restrict__ c2h,
                                                  const _Float16* __restrict__ Wfrag,
                                                  float* __restrict__ part) {
  __shared__ __align__(16) _Float16 P[2][64 * 64];  // [row][64 k], 128B rows, XOR-swz
  const int t = threadIdx.x;
  const int rowtile = blockIdx.x >> 2;
  const int kq = blockIdx.x & 3;
  const int rowbase = rowtile * 64;
  const int koff = kq * 2048;

  // ---- P-gen thread ids: row pr, 8 consecutive j at jq*8
  const int pr = t >> 3, jq = t & 7;
  const float2 rr = r2[rowbase + pr];
  const uchar* bp = bitsB + (size_t)(rowbase + pr) * (NN / 8) + (koff >> 3) + jq;
  const uint32* cp = c2h + koff + jq * 8;
  char* const pdst0 = (char*)&P[0][0] + pr * 128 + (((unsigned)(jq * 16)) ^ ((unsigned)((pr & 7) << 4)));
  char* const pdst1 = (char*)&P[1][0] + pr * 128 + (((unsigned)(jq * 16)) ^ ((unsigned)((pr & 7) << 4)));

  // ---- MFMA ids
  const int lane = t & 63, wave = t >> 6;
  const int wr = wave >> 2, wc = wave & 3;
  const int kgrp = lane >> 4, l15 = lane & 15;
  const unsigned asw = (unsigned)((l15 & 7) << 4);
  const int ar0 = (wr * 32 + l15) * 128;
  const int ar1 = ar0 + 16 * 128;

  f32x4 acc00 = {0.f, 0.f, 0.f, 0.f}, acc01 = {0.f, 0.f, 0.f, 0.f};
  f32x4 acc10 = {0.f, 0.f, 0.f, 0.f}, acc11 = {0.f, 0.f, 0.f, 0.f};

  uchar mb0, mb1;
  uint32 c0a[4], c0b[4], c1a[4], c1b[4];
  f16x8 B000, B001, B010, B011, B100, B101, B110, B111;

#define LOADALL(S, MB, CA, CB, Bq00, Bq01, Bq10, Bq11)                              \
  do {                                                                              \
    MB = bp[(S) * 8];                                                               \
    const uint4 _ca = *(const uint4*)(cp + (S) * 64);                               \
    const uint4 _cb = *(const uint4*)(cp + (S) * 64 + 4);                           \
    CA[0] = _ca.x; CA[1] = _ca.y; CA[2] = _ca.z; CA[3] = _ca.w;                     \
    CB[0] = _cb.x; CB[1] = _cb.y; CB[2] = _cb.z; CB[3] = _cb.w;                     \
    const _Float16* _b = Wfrag + ((size_t)((kq * 64 + (S) * 2) * 8 + wc * 2) * 64 + lane) * 8; \
    Bq00 = *(const f16x8*)(_b);                                                     \
    Bq01 = *(const f16x8*)(_b + 512);                                               \
    Bq10 = *(const f16x8*)(_b + 4096);                                              \
    Bq11 = *(const f16x8*)(_b + 4096 + 512);                                        \
  } while (0)

#define PGEN(DST, MB, CA, CB)                                                       \
  do {                                                                              \
    union { f16x2 h[4]; f16x8 v; } U;                                               \
    _Pragma("unroll") for (int _p = 0; _p < 4; ++_p) {                              \
      const uint32 cv0 = (_p < 2) ? CA[2 * _p] : CB[2 * (_p - 2)];                  \
      const uint32 cv1 = (_p < 2) ? CA[2 * _p + 1] : CB[2 * (_p - 2) + 1];          \
      const f16x2 ch0 = __builtin_bit_cast(f16x2, cv0);                             \
      const f16x2 ch1 = __builtin_bit_cast(f16x2, cv1);                             \
      const float m0 = fmaxf(rr.x * (float)ch0.x, rr.y * (float)ch0.y);             \
      const float m1 = fmaxf(rr.x * (float)ch1.x, rr.y * (float)ch1.y);             \
      const float w0 = ((MB >> (2 * _p)) & 1) ? m0 : 0.f;                           \
      const float w1 = ((MB >> (2 * _p + 1)) & 1) ? m1 : 0.f;                       \
      U.h[_p] = __builtin_bit_cast(f16x2, __builtin_amdgcn_cvt_pkrtz(w0, w1));      \
    }                                                                               \
    *(f16x8*)(DST) = U.v;                                                           \
  } while (0)

#define DO_MFMA(BUF, Bq00, Bq01, Bq10, Bq11)                                        \
  do {                                                                              \
    const char* _Pb = (const char*)&P[BUF][0];                                      \
    const f16x8 a00 = *(const f16x8*)(_Pb + ar0 + ((((unsigned)(kgrp * 16))) ^ asw));        \
    const f16x8 a01 = *(const f16x8*)(_Pb + ar0 + (((unsigned)(64 + kgrp * 16)) ^ asw));     \
    const f16x8 a10 = *(const f16x8*)(_Pb + ar1 + ((((unsigned)(kgrp * 16))) ^ asw));        \
    const f16x8 a11 = *(const f16x8*)(_Pb + ar1 + (((unsigned)(64 + kgrp * 16)) ^ asw));     \
    __builtin_amdgcn_s_setprio(1);                                                  \
    acc00 = __builtin_amdgcn_mfma_f32_16x16x32_f16(a00, Bq00, acc00, 0, 0, 0);      \
    acc01 = __builtin_amdgcn_mfma_f32_16x16x32_f16(a00, Bq01, acc01, 0, 0, 0);      \
    acc10 = __builtin_amdgcn_mfma_f32_16x16x32_f16(a10, Bq00, acc10, 0, 0, 0);      \
    acc11 = __builtin_amdgcn_mfma_f32_16x16x32_f16(a10, Bq01, acc11, 0, 0, 0);      \
    acc00 = __builtin_amdgcn_mfma_f32_16x16x32_f16(a01, Bq10, acc00, 0, 0, 0);      \
    acc01 = __builtin_amdgcn_mfma_f32_16x16x32_f16(a01, Bq11, acc01, 0, 0, 0);      \
    acc10 = __builtin_amdgcn_mfma_f32_16x16x32_f16(a11, Bq10, acc10, 0, 0, 0);      \
    acc11 = __builtin_amdgcn_mfma_f32_16x16x32_f16(a11, Bq11, acc11, 0, 0, 0);      \
    __builtin_amdgcn_s_setprio(0);                                                  \
  } while (0)

  // ---- prologue
  LOADALL(0, mb0, c0a, c0b, B000, B001, B010, B011);
  LOADALL(1, mb1, c1a, c1b, B100, B101, B110, B111);
  PGEN(pdst0, mb0, c0a, c0b);
  BARRIER_LDS();

  for (int s = 0; s < 32; s += 2) {
    // ---- even body: step s
    PGEN(pdst1, mb1, c1a, c1b);                       // step s+1
    DO_MFMA(0, B000, B001, B010, B011);               // step s
    if (s + 2 < 32) LOADALL(s + 2, mb0, c0a, c0b, B000, B001, B010, B011);
    BARRIER_LDS();
    // ---- odd body: step s+1
    DO_MFMA(1, B100, B101, B110, B111);               // step s+1
    if (s + 2 < 32) PGEN(pdst0, mb0, c0a, c0b);       // step s+2
    if (s + 3 < 32) LOADALL(s + 3, mb1, c1a, c1b, B100, B101, B110, B111);
    BARRIER_LDS();
  }

#undef LOADALL
#undef PGEN
#undef DO_MFMA

  // ---- epilogue: plain stores to this block's private partial buffer
  const int orow = rowbase + wr * 32 + kgrp * 4;
  const int ocol = wc * 32 + l15;
  float* aP = part + (size_t)kq * NN * FO + (size_t)orow * FO + ocol;
#pragma unroll
  for (int r = 0; r < 4; ++r) {
    aP[(size_t)r * FO] = acc00[r];
    aP[(size_t)r * FO + 16] = acc01[r];
    aP[(size_t)(16 + r) * FO] = acc10[r];
    aP[(size_t)(16 + r) * FO + 16] = acc11[r];
  }
}

// ---------------------------------------------------------------------------
// K5: out = elu(sum_q part[q] + corr)
// ---------------------------------------------------------------------------
__global__ __launch_bounds__(256) void k5_fin(const float* __restrict__ part,
                                              const float* __restrict__ corr,
                                              float* __restrict__ out) {
  const int idx = blockIdx.x * 256 + threadIdx.x;  // float4 index, 262144 total
  const float4 p0 = ((const float4*)part)[idx];
  const float4 p1 = ((const float4*)(part + (size_t)NN * FO))[idx];
  const float4 p2 = ((const float4*)(part + (size_t)2 * NN * FO))[idx];
  const float4 p3 = ((const float4*)(part + (size_t)3 * NN * FO))[idx];
  const float4 c = ((const float4*)corr)[idx & 31];
  float4 v;
  v.x = p0.x + p1.x + p2.x + p3.x + c.x;
  v.y = p0.y + p1.y + p2.y + p3.y + c.y;
  v.z = p0.z + p1.z + p2.z + p3.z + c.z;
  v.w = p0.w + p1.w + p2.w + p3.w + c.w;
  v.x = (v.x > 0.f) ? v.x : (expf(v.x) - 1.f);
  v.y = (v.y > 0.f) ? v.y : (expf(v.y) - 1.f);
  v.z = (v.z > 0.f) ? v.z : (expf(v.z) - 1.f);
  v.w = (v.w > 0.f) ? v.w : (expf(v.w) - 1.f);
  ((float4*)out)[idx] = v;
}

// ---------------------------------------------------------------------------
extern "C" void kernel_launch(void* const* d_in, const int* in_sizes, int n_in,
                              void* d_out, int out_size, void* d_ws, size_t ws_size,
                              hipStream_t stream) {
  const float* h = (const float*)d_in[0];
  const int* adj = (const int*)d_in[1];
  const float* W = (const float*)d_in[2];
  const float* b = (const float*)d_in[3];
  const float* a = (const float*)d_in[4];
  float* out = (float*)d_out;
  char* ws = (char*)d_ws;

  // workspace carve (~39 MB total; d_ws is ~1 GB per harness poison-fill size)
  float* Wh = (float*)(ws + 0);                                   // 4 MB  [k1..k3]
  _Float16* Wfrag = (_Float16*)(ws + 0x400000);                   // 2 MB  [k3..k4]
  uchar* bits = (uchar*)(ws + 0x600000);                          // 8 MB  [k2..k4]
  float2* zpart = (float2*)(ws + 0xE00000);                       // 8 MB  [k2..k3]
  float4* r4 = (float4*)(ws + 0x1600000);                         // 128 KB
  float4* c4 = (float4*)(ws + 0x1620000);                         // 128 KB
  float2* r2 = (float2*)(ws + 0x1640000);                         // 64 KB
  uint32* c2h = (uint32*)(ws + 0x1650000);                        // 32 KB
  float* s2x = (float*)(ws + 0x1658000);                          // 32 KB
  float* corr = (float*)(ws + 0x1660000);                         // 512 B
  float* part = (float*)(ws + 0x1700000);                         // 16 MB [k4..k5]

  k1_wh<<<NN / 32, 256, 0, stream>>>(h, W, b, Wh);
  k1b_sv<<<NN / 4, 256, 0, stream>>>(Wh, a, r4, c4, r2, c2h, s2x, corr);
  k2_stats<<<512, 256, 0, stream>>>(adj, r4, s2x, bits, zpart);
  k3_scale<<<NN / 64, 256, 0, stream>>>(Wh, c4, zpart, Wfrag, corr);
  k4_main<<<512, 512, 0, stream>>>(bits, r2, c2h, Wfrag, part);
  k5_fin<<<(NN * FO / 4) / 256, 256, 0, stream>>>(part, corr, out);
}